// Round 1
// baseline (297.687 us; speedup 1.0000x reference)
//
#include <hip/hip_runtime.h>
#include <math.h>

#define N_NODES 8192
#define N_EDGES 65536
#define F_IN    512
#define HID1    4096
#define HID2    1024
#define F_OUT   10
#define H3_STRIDE 16
#define W3B_STRIDE 1032   // padded K-stride of bf16 W3^T rows

typedef __bf16 bf16x8 __attribute__((ext_vector_type(8)));
typedef float floatx4 __attribute__((ext_vector_type(4)));
typedef float floatx16 __attribute__((ext_vector_type(16)));

static __device__ __forceinline__ unsigned short f2bf(float f) {
    union { float f; unsigned u; } v; v.f = f;
    unsigned r = v.u + 0x7fffu + ((v.u >> 16) & 1u);   // RNE
    return (unsigned short)(r >> 16);
}
static __device__ __forceinline__ float bf2f(unsigned short u) {
    union { unsigned u; float f; } v; v.u = ((unsigned)u) << 16;
    return v.f;
}
static __device__ __forceinline__ void unpack8(uint4 r, float* f) {
    union { unsigned u; float v; } c;
    c.u = r.x << 16;          f[0] = c.v;
    c.u = r.x & 0xffff0000u;  f[1] = c.v;
    c.u = r.y << 16;          f[2] = c.v;
    c.u = r.y & 0xffff0000u;  f[3] = c.v;
    c.u = r.z << 16;          f[4] = c.v;
    c.u = r.z & 0xffff0000u;  f[5] = c.v;
    c.u = r.w << 16;          f[6] = c.v;
    c.u = r.w & 0xffff0000u;  f[7] = c.v;
}
static __device__ __forceinline__ uint4 pack8(const float* f) {
    uint4 o;
    o.x = (unsigned)f2bf(f[0]) | ((unsigned)f2bf(f[1]) << 16);
    o.y = (unsigned)f2bf(f[2]) | ((unsigned)f2bf(f[3]) << 16);
    o.z = (unsigned)f2bf(f[4]) | ((unsigned)f2bf(f[5]) << 16);
    o.w = (unsigned)f2bf(f[6]) | ((unsigned)f2bf(f[7]) << 16);
    return o;
}

// ---------------------------------------------------------------------------
// hist+scan (one block): deg[] via LDS histogram, exclusive scan -> row_ptr,
// cnt[] zeroing.
// ---------------------------------------------------------------------------
__global__ __launch_bounds__(1024) void hist_scan_kernel(
        const int* __restrict__ ei, int* __restrict__ deg,
        int* __restrict__ row_ptr, int* __restrict__ cnt) {
    __shared__ int hist[N_NODES];        // 32 KB
    __shared__ int sums[1024];
    int t = threadIdx.x;
#pragma unroll
    for (int i = 0; i < 8; i++) hist[t + i * 1024] = 0;
    __syncthreads();
#pragma unroll
    for (int i = 0; i < 64; i++) {
        int d = ei[N_EDGES + i * 1024 + t];
        atomicAdd(&hist[d], 1);
    }
    __syncthreads();
    int base = t * 8;
    int local[8], run = 0;
#pragma unroll
    for (int i = 0; i < 8; i++) {
        int dv = hist[base + i];
        deg[base + i] = dv;
        cnt[base + i] = 0;
        local[i] = run; run += dv;
    }
    sums[t] = run;
    __syncthreads();
    for (int off = 1; off < 1024; off <<= 1) {
        int val = (t >= off) ? sums[t - off] : 0;
        __syncthreads();
        sums[t] += val;
        __syncthreads();
    }
    int offset = (t == 0) ? 0 : sums[t - 1];
#pragma unroll
    for (int i = 0; i < 8; i++) row_ptr[base + i] = offset + local[i];
    if (t == 1023) row_ptr[N_NODES] = sums[1023];
}

// ---------------------------------------------------------------------------
// megaprep: fill CSR (blocks 0..255) + xcvt (256..4351) + W1^T (4352..6399)
// + W2^T (6400..10495) + W3 bf16 cvt (10496). One launch.
// ---------------------------------------------------------------------------
static __device__ __forceinline__ void transpose_body(
        const float* __restrict__ W, unsigned short* __restrict__ Wt,
        int K, int N, int k0, int n0, int tid, float (*t)[33]) {
    int c = tid & 31, r8 = tid >> 5;
#pragma unroll
    for (int i = 0; i < 4; i++) {
        int r = r8 + i * 8;
        t[r][c] = W[(size_t)(k0 + r) * N + n0 + c];
    }
    __syncthreads();
#pragma unroll
    for (int i = 0; i < 4; i++) {
        int r = r8 + i * 8;
        Wt[(size_t)(n0 + r) * K + k0 + c] = f2bf(t[c][r]);
    }
}

__global__ __launch_bounds__(256) void megaprep_kernel(
        const int* __restrict__ ei, const int* __restrict__ deg,
        const int* __restrict__ row_ptr, int* __restrict__ cnt,
        int* __restrict__ csr_src, float* __restrict__ csr_w,
        const float* __restrict__ x, unsigned short* __restrict__ xb,
        const float* __restrict__ W1, unsigned short* __restrict__ W1t,
        const float* __restrict__ W2, unsigned short* __restrict__ W2t,
        const float* __restrict__ W3, unsigned short* __restrict__ w3b) {
    __shared__ float t[32][33];
    int b = blockIdx.x, tid = threadIdx.x;
    if (b < 256) {
        int e = b * 256 + tid;
        int s = ei[e];
        int d = ei[N_EDGES + e];
        int slot = row_ptr[d] + atomicAdd(&cnt[d], 1);
        csr_src[slot] = s;
        csr_w[slot] = rsqrtf((float)((deg[s] + 1) * (deg[d] + 1)));
    } else if (b < 4352) {
        int i = (b - 256) * 256 + tid;
        float4 a = ((const float4*)x)[i];
        ushort4 o;
        o.x = f2bf(a.x); o.y = f2bf(a.y); o.z = f2bf(a.z); o.w = f2bf(a.w);
        ((ushort4*)xb)[i] = o;
    } else if (b < 6400) {
        int bb = b - 4352;                       // W1: K=512, N=4096
        transpose_body(W1, W1t, F_IN, HID1, (bb >> 7) * 32, (bb & 127) * 32, tid, t);
    } else if (b < 10496) {
        int bb = b - 6400;                       // W2: K=4096, N=1024
        transpose_body(W2, W2t, HID1, HID2, (bb >> 5) * 32, (bb & 31) * 32, tid, t);
    } else {
        // W3 [1024,10] f32 -> w3b [10][W3B_STRIDE] bf16 (transposed)
        for (int i = tid; i < HID2 * F_OUT; i += 256) {
            int k = i / F_OUT, c = i % F_OUT;
            w3b[c * W3B_STRIDE + k] = f2bf(W3[i]);
        }
    }
}

// ---------------------------------------------------------------------------
// agg1: agg_x[v,:] = sum_e w_e*xb[src,:] + xb[v,:]/(deg+1) -> bf16
// 1 node per wave (64 lanes x uint4 = 1 KB row), 4 nodes/block. Unroll x4.
// ---------------------------------------------------------------------------
__global__ __launch_bounds__(256) void agg1_kernel(
        const unsigned short* __restrict__ xb, const int* __restrict__ row_ptr,
        const int* __restrict__ csr_src, const float* __restrict__ csr_w,
        const int* __restrict__ deg, unsigned short* __restrict__ out) {
    int v = blockIdx.x * 4 + (threadIdx.x >> 6);
    int t = threadIdx.x & 63;
    const uint4* xp = (const uint4*)xb;        // row stride 64 uint4
    float sw = 1.0f / (float)(deg[v] + 1);
    float acc[8], tmp[8];
    unpack8(xp[(size_t)v * 64 + t], tmp);
#pragma unroll
    for (int j = 0; j < 8; j++) acc[j] = sw * tmp[j];
    int e = row_ptr[v], end = row_ptr[v + 1];
    for (; e + 4 <= end; e += 4) {
        int s0 = csr_src[e], s1 = csr_src[e + 1];
        int s2 = csr_src[e + 2], s3 = csr_src[e + 3];
        float w0 = csr_w[e], w1 = csr_w[e + 1];
        float w2 = csr_w[e + 2], w3 = csr_w[e + 3];
        float f0[8], f1[8], f2[8], f3[8];
        unpack8(xp[(size_t)s0 * 64 + t], f0);
        unpack8(xp[(size_t)s1 * 64 + t], f1);
        unpack8(xp[(size_t)s2 * 64 + t], f2);
        unpack8(xp[(size_t)s3 * 64 + t], f3);
#pragma unroll
        for (int j = 0; j < 8; j++)
            acc[j] += w0 * f0[j] + w1 * f1[j] + w2 * f2[j] + w3 * f3[j];
    }
    for (; e < end; e++) {
        int s = csr_src[e];
        float w = csr_w[e];
        float f0[8];
        unpack8(xp[(size_t)s * 64 + t], f0);
#pragma unroll
        for (int j = 0; j < 8; j++) acc[j] += w * f0[j];
    }
    ((uint4*)out)[(size_t)v * 64 + t] = pack8(acc);
}

// ---------------------------------------------------------------------------
// agg2 + gemm3 fused. Unroll x4 on the edge loop.
// ---------------------------------------------------------------------------
__global__ __launch_bounds__(256) void agg2_gemm3_kernel(
        const unsigned short* __restrict__ h, const int* __restrict__ row_ptr,
        const int* __restrict__ csr_src, const float* __restrict__ csr_w,
        const int* __restrict__ deg, const float* __restrict__ b2,
        const unsigned short* __restrict__ w3b, float* __restrict__ H3) {
    __shared__ unsigned short w3s[F_OUT * W3B_STRIDE];   // ~20.2 KB
    __shared__ float red[4][F_OUT];
    int tid = threadIdx.x;
    for (int i = tid; i < F_OUT * W3B_STRIDE; i += 256) w3s[i] = w3b[i];
    __syncthreads();
    int half = tid >> 7;
    int t = tid & 127;
    int v = blockIdx.x * 2 + half;
    const uint4* hp = (const uint4*)h;   // row stride 128 uint4
    float sw = 1.0f / (float)(deg[v] + 1);
    float acc[8], tmp[8];
    unpack8(hp[(size_t)v * 128 + t], tmp);
#pragma unroll
    for (int j = 0; j < 8; j++) acc[j] = sw * tmp[j];
    int e = row_ptr[v], end = row_ptr[v + 1];
    for (; e + 4 <= end; e += 4) {
        int s0 = csr_src[e], s1 = csr_src[e + 1];
        int s2 = csr_src[e + 2], s3 = csr_src[e + 3];
        float w0 = csr_w[e], w1 = csr_w[e + 1];
        float w2 = csr_w[e + 2], w3 = csr_w[e + 3];
        float f0[8], f1[8], f2[8], f3[8];
        unpack8(hp[(size_t)s0 * 128 + t], f0);
        unpack8(hp[(size_t)s1 * 128 + t], f1);
        unpack8(hp[(size_t)s2 * 128 + t], f2);
        unpack8(hp[(size_t)s3 * 128 + t], f3);
#pragma unroll
        for (int j = 0; j < 8; j++)
            acc[j] += w0 * f0[j] + w1 * f1[j] + w2 * f2[j] + w3 * f3[j];
    }
    for (; e < end; e++) {
        int s = csr_src[e];
        float w = csr_w[e];
        float f0[8];
        unpack8(hp[(size_t)s * 128 + t], f0);
#pragma unroll
        for (int j = 0; j < 8; j++) acc[j] += w * f0[j];
    }
    float4 b4a = ((const float4*)b2)[t * 2];
    float4 b4b = ((const float4*)b2)[t * 2 + 1];
    acc[0] = fmaxf(acc[0] + b4a.x, 0.0f); acc[1] = fmaxf(acc[1] + b4a.y, 0.0f);
    acc[2] = fmaxf(acc[2] + b4a.z, 0.0f); acc[3] = fmaxf(acc[3] + b4a.w, 0.0f);
    acc[4] = fmaxf(acc[4] + b4b.x, 0.0f); acc[5] = fmaxf(acc[5] + b4b.y, 0.0f);
    acc[6] = fmaxf(acc[6] + b4b.z, 0.0f); acc[7] = fmaxf(acc[7] + b4b.w, 0.0f);

    float partial[F_OUT];
#pragma unroll
    for (int c = 0; c < F_OUT; c++) {
        float wf[8];
        unpack8(*(const uint4*)&w3s[c * W3B_STRIDE + t * 8], wf);
        partial[c] = acc[0] * wf[0] + acc[1] * wf[1] + acc[2] * wf[2] + acc[3] * wf[3]
                   + acc[4] * wf[4] + acc[5] * wf[5] + acc[6] * wf[6] + acc[7] * wf[7];
    }
#pragma unroll
    for (int c = 0; c < F_OUT; c++) {
#pragma unroll
        for (int off = 32; off > 0; off >>= 1)
            partial[c] += __shfl_xor(partial[c], off, 64);
    }
    int wave = tid >> 6, lane = tid & 63;
    if (lane == 0) {
#pragma unroll
        for (int c = 0; c < F_OUT; c++) red[wave][c] = partial[c];
    }
    __syncthreads();
    if (tid < 2 * F_OUT) {
        int hh = tid / F_OUT, c = tid % F_OUT;
        H3[(size_t)(blockIdx.x * 2 + hh) * H3_STRIDE + c] =
            red[hh * 2][c] + red[hh * 2 + 1][c];
    }
}

// ---------------------------------------------------------------------------
// Pipelined GEMM (T3+T4+T5): BM=128, BN=256, BK=64, 8 waves (512 thr),
// per-wave 64x64 (2x2 of 32x32x16 MFMA). 3-buffer LDS rotation (144 KB),
// counted vmcnt(6): tile t+2's loads stay in flight across the per-tile
// barrier while tile t computes. Raw s_barrier (no vmcnt(0) drain).
// XOR swizzle on both the global source chunk and the ds_read address
// (conflict-free; identical scheme to the verified 2-barrier kernel).
// ---------------------------------------------------------------------------
#define GP_STAGE(t_, q_) do {                                                  \
    unsigned short* As_ = lds + (q_) * 24576;                                  \
    unsigned short* Bs_ = As_ + 8192;                                          \
    int k0_ = (t_) * 64;                                                       \
    _Pragma("unroll")                                                          \
    for (int j = 0; j < 2; j++) {           /* A: 128x64 = 1024 16B slots */   \
        int idx = j * 512 + tid;                                               \
        int r = idx >> 3;                                                      \
        int kc = (idx & 7) ^ (r & 7);                                          \
        __builtin_amdgcn_global_load_lds(                                      \
            (const __attribute__((address_space(1))) void*)(Abase + (size_t)r * K + k0_ + kc * 8), \
            (__attribute__((address_space(3))) void*)(&As_[idx * 8]), 16, 0, 0); \
    }                                                                          \
    _Pragma("unroll")                                                          \
    for (int j = 0; j < 4; j++) {           /* B: 256x64 = 2048 16B slots */   \
        int idx = j * 512 + tid;                                               \
        int r = idx >> 3;                                                      \
        int kc = (idx & 7) ^ (r & 7);                                          \
        __builtin_amdgcn_global_load_lds(                                      \
            (const __attribute__((address_space(1))) void*)(Bbase + (size_t)r * K + k0_ + kc * 8), \
            (__attribute__((address_space(3))) void*)(&Bs_[idx * 8]), 16, 0, 0); \
    }                                                                          \
} while (0)

template <bool OUT_BF16, bool BIAS, bool RELU>
__global__ __launch_bounds__(512) void gemm_pipe_kernel(
        const unsigned short* __restrict__ A,   // [M,K] bf16
        const unsigned short* __restrict__ Bt,  // [N,K] bf16
        const float* __restrict__ bias,         // [N] or null
        void* __restrict__ C,                   // [M,N] bf16 or f32
        int M, int N, int K) {
    __shared__ unsigned short lds[3 * 24576];   // 3 x (A 16KB + B 32KB) = 144 KB
    int tid = threadIdx.x;
    int wave = tid >> 6, lane = tid & 63;
    int wm = wave & 1, wn = wave >> 1;          // 2M x 4N wave grid
    int lrow = lane & 31, lhalf = lane >> 5;

    // XCD-aware bijective swizzle (grid % 8 == 0), ntile-major so the 32
    // blocks of one XCD share a B panel (L2-resident).
    int nwg = gridDim.x;
    int cpx = nwg >> 3;
    int b = blockIdx.x;
    int swz = (b & 7) * cpx + (b >> 3);
    int nm = M >> 7;                            // number of m-tiles
    int ntile = swz / nm;
    int mtile = swz - ntile * nm;

    const unsigned short* Abase = A + (size_t)mtile * 128 * K;
    const unsigned short* Bbase = Bt + (size_t)ntile * 256 * K;

    floatx16 acc[2][2] = {};
    int NT = K >> 6;

    // Prologue: stage tiles 0 and 1; wait only for tile 0 (6 = tile 1 in flight)
    GP_STAGE(0, 0);
    GP_STAGE(1, 1);
    asm volatile("s_waitcnt vmcnt(6)" ::: "memory");
    __builtin_amdgcn_s_barrier();

    int q = 0, qn = 2;                          // current buf, (t+2)%3 buf
    for (int t = 0; t < NT; t++) {
        unsigned short* As_ = lds + q * 24576;
        unsigned short* Bs_ = As_ + 8192;
#pragma unroll
        for (int kk = 0; kk < 4; kk++) {        // 4 k16-phases
            bf16x8 af[2], bfr[2];
            int c = kk * 2 + lhalf;             // 16B chunk index 0..7
#pragma unroll
            for (int mt = 0; mt < 2; mt++) {
                int R = wm * 64 + mt * 32 + lrow;
                af[mt] = *(const bf16x8*)&As_[(R * 8 + (c ^ (R & 7))) * 8];
            }
#pragma unroll
            for (int nt = 0; nt < 2; nt++) {
                int R = wn * 64 + nt * 32 + lrow;
                bfr[nt] = *(const bf16x8*)&Bs_[(R * 8 + (c ^ (R & 7))) * 8];
            }
            if (kk == 0 && t + 2 < NT) {
                GP_STAGE(t + 2, qn);            // prefetch under this tile's MFMAs
            }
            __builtin_amdgcn_s_setprio(1);
#pragma unroll
            for (int mt = 0; mt < 2; mt++)
#pragma unroll
                for (int nt = 0; nt < 2; nt++)
                    acc[mt][nt] = __builtin_amdgcn_mfma_f32_32x32x16_bf16(
                        af[mt], bfr[nt], acc[mt][nt], 0, 0, 0);
            __builtin_amdgcn_s_setprio(0);
        }
        // Publish tile t+1: wait for its 6 loads only (t+2's 6 stay in flight).
        if (t + 2 < NT)
            asm volatile("s_waitcnt vmcnt(6)" ::: "memory");
        else
            asm volatile("s_waitcnt vmcnt(0)" ::: "memory");
        __builtin_amdgcn_s_barrier();
        q = (q == 2) ? 0 : q + 1;
        qn = (qn == 2) ? 0 : qn + 1;
    }

#pragma unroll
    for (int mt = 0; mt < 2; mt++) {
#pragma unroll
        for (int nt = 0; nt < 2; nt++) {
            int col = ntile * 256 + wn * 64 + nt * 32 + lrow;
            float bv = BIAS ? bias[col] : 0.0f;
#pragma unroll
            for (int reg = 0; reg < 16; reg++) {
                int row = mtile * 128 + wm * 64 + mt * 32 + (reg & 3) + 8 * (reg >> 2) + 4 * lhalf;
                float v = acc[mt][nt][reg] + bv;
                if (RELU) v = fmaxf(v, 0.0f);
                if (OUT_BF16)
                    ((unsigned short*)C)[(size_t)row * N + col] = f2bf(v);
                else
                    ((float*)C)[(size_t)row * N + col] = v;
            }
        }
    }
}

// ---------------------------------------------------------------------------
// Final: aggregate h3 (stride 16), add b3, log_softmax per node.
// ---------------------------------------------------------------------------
__global__ void final_kernel(const float* __restrict__ h3, const int* __restrict__ row_ptr,
                             const int* __restrict__ csr_src, const float* __restrict__ csr_w,
                             const int* __restrict__ deg, const float* __restrict__ b3,
                             float* __restrict__ out) {
    int v = blockIdx.x * blockDim.x + threadIdx.x;
    if (v >= N_NODES) return;
    const float4* h4 = (const float4*)h3;
    float sw = 1.0f / (float)(deg[v] + 1);
    float a[12];
    *(float4*)&a[0] = h4[v * 4];
    *(float4*)&a[4] = h4[v * 4 + 1];
    *(float4*)&a[8] = h4[v * 4 + 2];
    float acc[F_OUT];
#pragma unroll
    for (int c = 0; c < F_OUT; c++) acc[c] = b3[c] + sw * a[c];
    int end = row_ptr[v + 1];
    for (int e = row_ptr[v]; e < end; e++) {
        int s = csr_src[e];
        float w = csr_w[e];
        float bsrc[12];
        *(float4*)&bsrc[0] = h4[s * 4];
        *(float4*)&bsrc[4] = h4[s * 4 + 1];
        *(float4*)&bsrc[8] = h4[s * 4 + 2];
#pragma unroll
        for (int c = 0; c < F_OUT; c++) acc[c] += w * bsrc[c];
    }
    float m = acc[0];
#pragma unroll
    for (int c = 1; c < F_OUT; c++) m = fmaxf(m, acc[c]);
    float ssum = 0.0f;
#pragma unroll
    for (int c = 0; c < F_OUT; c++) ssum += expf(acc[c] - m);
    float l = logf(ssum);
#pragma unroll
    for (int c = 0; c < F_OUT; c++) out[v * F_OUT + c] = acc[c] - m - l;
}

// ---------------------------------------------------------------------------
// Launch (7 dispatches)
// ---------------------------------------------------------------------------
extern "C" void kernel_launch(void* const* d_in, const int* in_sizes, int n_in,
                              void* d_out, int out_size, void* d_ws, size_t ws_size,
                              hipStream_t stream) {
    const float* x  = (const float*)d_in[0];
    const float* W1 = (const float*)d_in[1];
    const float* b1 = (const float*)d_in[2];
    const float* W2 = (const float*)d_in[3];
    const float* b2 = (const float*)d_in[4];
    const float* W3 = (const float*)d_in[5];
    const float* b3 = (const float*)d_in[6];
    const int*   ei = (const int*)d_in[7];
    float* out = (float*)d_out;

    char* p = (char*)d_ws;
    int*   deg     = (int*)p;    p += N_NODES * 4;
    int*   cnt     = (int*)p;    p += N_NODES * 4;
    int*   row_ptr = (int*)p;    p += 33024;
    int*   csr_src = (int*)p;    p += N_EDGES * 4;
    float* csr_w   = (float*)p;  p += N_EDGES * 4;
    float* h3      = (float*)p;  p += N_NODES * H3_STRIDE * 4;
    unsigned short* w3b = (unsigned short*)p; p += (F_OUT * W3B_STRIDE * 2 + 255) / 256 * 256;
    unsigned short* xb    = (unsigned short*)p; p += (size_t)N_NODES * F_IN * 2;
    unsigned short* agg_x = (unsigned short*)p; p += (size_t)N_NODES * F_IN * 2;
    unsigned short* W1t   = (unsigned short*)p; p += (size_t)HID1 * F_IN * 2;
    unsigned short* W2t   = (unsigned short*)p; p += (size_t)HID2 * HID1 * 2;
    unsigned short* h1    = (unsigned short*)p; p += (size_t)N_NODES * HID1 * 2;
    unsigned short* h2pre = (unsigned short*)p; p += (size_t)N_NODES * HID2 * 2;

    // Graph preprocessing + all conversions (2 launches)
    hist_scan_kernel<<<1, 1024, 0, stream>>>(ei, deg, row_ptr, cnt);
    megaprep_kernel<<<10497, 256, 0, stream>>>(ei, deg, row_ptr, cnt, csr_src, csr_w,
                                               x, xb, W1, W1t, W2, W2t, W3, w3b);

    // Layer 1
    agg1_kernel<<<N_NODES / 4, 256, 0, stream>>>(xb, row_ptr, csr_src, csr_w, deg, agg_x);
    gemm_pipe_kernel<true, true, true><<<(N_NODES / 128) * (HID1 / 256), 512, 0, stream>>>(
        agg_x, W1t, b1, h1, N_NODES, HID1, F_IN);

    // Layer 2 (pipelined: counted vmcnt, 3-buffer LDS)
    gemm_pipe_kernel<true, false, false><<<(N_NODES / 128) * (HID2 / 256), 512, 0, stream>>>(
        h1, W2t, nullptr, h2pre, N_NODES, HID2, HID1);

    // Layer 2 aggregation + Layer 3 GEMM fused
    agg2_gemm3_kernel<<<N_NODES / 2, 256, 0, stream>>>(h2pre, row_ptr, csr_src, csr_w,
                                                       deg, b2, w3b, h3);

    // Output
    final_kernel<<<N_NODES / 256, 256, 0, stream>>>(h3, row_ptr, csr_src, csr_w, deg, b3, out);
}

// Round 2
// 293.088 us; speedup vs baseline: 1.0157x; 1.0157x over previous
//
#include <hip/hip_runtime.h>
#include <math.h>

#define N_NODES 8192
#define N_EDGES 65536
#define F_IN    512
#define HID1    4096
#define HID2    1024
#define F_OUT   10
#define H3_STRIDE 16
#define W3B_STRIDE 1032   // padded K-stride of bf16 W3^T rows

typedef __bf16 bf16x8 __attribute__((ext_vector_type(8)));
typedef float floatx4 __attribute__((ext_vector_type(4)));
typedef float floatx16 __attribute__((ext_vector_type(16)));

static __device__ __forceinline__ unsigned short f2bf(float f) {
    union { float f; unsigned u; } v; v.f = f;
    unsigned r = v.u + 0x7fffu + ((v.u >> 16) & 1u);   // RNE
    return (unsigned short)(r >> 16);
}
static __device__ __forceinline__ float bf2f(unsigned short u) {
    union { unsigned u; float f; } v; v.u = ((unsigned)u) << 16;
    return v.f;
}
static __device__ __forceinline__ void unpack8(uint4 r, float* f) {
    union { unsigned u; float v; } c;
    c.u = r.x << 16;          f[0] = c.v;
    c.u = r.x & 0xffff0000u;  f[1] = c.v;
    c.u = r.y << 16;          f[2] = c.v;
    c.u = r.y & 0xffff0000u;  f[3] = c.v;
    c.u = r.z << 16;          f[4] = c.v;
    c.u = r.z & 0xffff0000u;  f[5] = c.v;
    c.u = r.w << 16;          f[6] = c.v;
    c.u = r.w & 0xffff0000u;  f[7] = c.v;
}
static __device__ __forceinline__ uint4 pack8(const float* f) {
    uint4 o;
    o.x = (unsigned)f2bf(f[0]) | ((unsigned)f2bf(f[1]) << 16);
    o.y = (unsigned)f2bf(f[2]) | ((unsigned)f2bf(f[3]) << 16);
    o.z = (unsigned)f2bf(f[4]) | ((unsigned)f2bf(f[5]) << 16);
    o.w = (unsigned)f2bf(f[6]) | ((unsigned)f2bf(f[7]) << 16);
    return o;
}

// ---------------------------------------------------------------------------
// hist+scan (one block): deg[] via LDS histogram, exclusive scan -> row_ptr,
// cnt[] zeroing.
// ---------------------------------------------------------------------------
__global__ __launch_bounds__(1024) void hist_scan_kernel(
        const int* __restrict__ ei, int* __restrict__ deg,
        int* __restrict__ row_ptr, int* __restrict__ cnt) {
    __shared__ int hist[N_NODES];        // 32 KB
    __shared__ int sums[1024];
    int t = threadIdx.x;
#pragma unroll
    for (int i = 0; i < 8; i++) hist[t + i * 1024] = 0;
    __syncthreads();
#pragma unroll
    for (int i = 0; i < 64; i++) {
        int d = ei[N_EDGES + i * 1024 + t];
        atomicAdd(&hist[d], 1);
    }
    __syncthreads();
    int base = t * 8;
    int local[8], run = 0;
#pragma unroll
    for (int i = 0; i < 8; i++) {
        int dv = hist[base + i];
        deg[base + i] = dv;
        cnt[base + i] = 0;
        local[i] = run; run += dv;
    }
    sums[t] = run;
    __syncthreads();
    for (int off = 1; off < 1024; off <<= 1) {
        int val = (t >= off) ? sums[t - off] : 0;
        __syncthreads();
        sums[t] += val;
        __syncthreads();
    }
    int offset = (t == 0) ? 0 : sums[t - 1];
#pragma unroll
    for (int i = 0; i < 8; i++) row_ptr[base + i] = offset + local[i];
    if (t == 1023) row_ptr[N_NODES] = sums[1023];
}

// ---------------------------------------------------------------------------
// megaprep: fill CSR (blocks 0..255) + xcvt (256..4351) + W1^T (4352..6399)
// + W2^T (6400..10495) + W3 bf16 cvt (10496). One launch.
// ---------------------------------------------------------------------------
static __device__ __forceinline__ void transpose_body(
        const float* __restrict__ W, unsigned short* __restrict__ Wt,
        int K, int N, int k0, int n0, int tid, float (*t)[33]) {
    int c = tid & 31, r8 = tid >> 5;
#pragma unroll
    for (int i = 0; i < 4; i++) {
        int r = r8 + i * 8;
        t[r][c] = W[(size_t)(k0 + r) * N + n0 + c];
    }
    __syncthreads();
#pragma unroll
    for (int i = 0; i < 4; i++) {
        int r = r8 + i * 8;
        Wt[(size_t)(n0 + r) * K + k0 + c] = f2bf(t[c][r]);
    }
}

__global__ __launch_bounds__(256) void megaprep_kernel(
        const int* __restrict__ ei, const int* __restrict__ deg,
        const int* __restrict__ row_ptr, int* __restrict__ cnt,
        int* __restrict__ csr_src, float* __restrict__ csr_w,
        const float* __restrict__ x, unsigned short* __restrict__ xb,
        const float* __restrict__ W1, unsigned short* __restrict__ W1t,
        const float* __restrict__ W2, unsigned short* __restrict__ W2t,
        const float* __restrict__ W3, unsigned short* __restrict__ w3b) {
    __shared__ float t[32][33];
    int b = blockIdx.x, tid = threadIdx.x;
    if (b < 256) {
        int e = b * 256 + tid;
        int s = ei[e];
        int d = ei[N_EDGES + e];
        int slot = row_ptr[d] + atomicAdd(&cnt[d], 1);
        csr_src[slot] = s;
        csr_w[slot] = rsqrtf((float)((deg[s] + 1) * (deg[d] + 1)));
    } else if (b < 4352) {
        int i = (b - 256) * 256 + tid;
        float4 a = ((const float4*)x)[i];
        ushort4 o;
        o.x = f2bf(a.x); o.y = f2bf(a.y); o.z = f2bf(a.z); o.w = f2bf(a.w);
        ((ushort4*)xb)[i] = o;
    } else if (b < 6400) {
        int bb = b - 4352;                       // W1: K=512, N=4096
        transpose_body(W1, W1t, F_IN, HID1, (bb >> 7) * 32, (bb & 127) * 32, tid, t);
    } else if (b < 10496) {
        int bb = b - 6400;                       // W2: K=4096, N=1024
        transpose_body(W2, W2t, HID1, HID2, (bb >> 5) * 32, (bb & 31) * 32, tid, t);
    } else {
        // W3 [1024,10] f32 -> w3b [10][W3B_STRIDE] bf16 (transposed)
        for (int i = tid; i < HID2 * F_OUT; i += 256) {
            int k = i / F_OUT, c = i % F_OUT;
            w3b[c * W3B_STRIDE + k] = f2bf(W3[i]);
        }
    }
}

// ---------------------------------------------------------------------------
// agg1: agg_x[v,:] = sum_e w_e*xb[src,:] + xb[v,:]/(deg+1) -> bf16
// 1 node per wave (64 lanes x uint4 = 1 KB row), 4 nodes/block. Unroll x4.
// ---------------------------------------------------------------------------
__global__ __launch_bounds__(256) void agg1_kernel(
        const unsigned short* __restrict__ xb, const int* __restrict__ row_ptr,
        const int* __restrict__ csr_src, const float* __restrict__ csr_w,
        const int* __restrict__ deg, unsigned short* __restrict__ out) {
    int v = blockIdx.x * 4 + (threadIdx.x >> 6);
    int t = threadIdx.x & 63;
    const uint4* xp = (const uint4*)xb;        // row stride 64 uint4
    float sw = 1.0f / (float)(deg[v] + 1);
    float acc[8], tmp[8];
    unpack8(xp[(size_t)v * 64 + t], tmp);
#pragma unroll
    for (int j = 0; j < 8; j++) acc[j] = sw * tmp[j];
    int e = row_ptr[v], end = row_ptr[v + 1];
    for (; e + 4 <= end; e += 4) {
        int s0 = csr_src[e], s1 = csr_src[e + 1];
        int s2 = csr_src[e + 2], s3 = csr_src[e + 3];
        float w0 = csr_w[e], w1 = csr_w[e + 1];
        float w2 = csr_w[e + 2], w3 = csr_w[e + 3];
        float f0[8], f1[8], f2[8], f3[8];
        unpack8(xp[(size_t)s0 * 64 + t], f0);
        unpack8(xp[(size_t)s1 * 64 + t], f1);
        unpack8(xp[(size_t)s2 * 64 + t], f2);
        unpack8(xp[(size_t)s3 * 64 + t], f3);
#pragma unroll
        for (int j = 0; j < 8; j++)
            acc[j] += w0 * f0[j] + w1 * f1[j] + w2 * f2[j] + w3 * f3[j];
    }
    for (; e < end; e++) {
        int s = csr_src[e];
        float w = csr_w[e];
        float f0[8];
        unpack8(xp[(size_t)s * 64 + t], f0);
#pragma unroll
        for (int j = 0; j < 8; j++) acc[j] += w * f0[j];
    }
    ((uint4*)out)[(size_t)v * 64 + t] = pack8(acc);
}

// ---------------------------------------------------------------------------
// agg2 + gemm3 fused. Unroll x4 on the edge loop.
// ---------------------------------------------------------------------------
__global__ __launch_bounds__(256) void agg2_gemm3_kernel(
        const unsigned short* __restrict__ h, const int* __restrict__ row_ptr,
        const int* __restrict__ csr_src, const float* __restrict__ csr_w,
        const int* __restrict__ deg, const float* __restrict__ b2,
        const unsigned short* __restrict__ w3b, float* __restrict__ H3) {
    __shared__ unsigned short w3s[F_OUT * W3B_STRIDE];   // ~20.2 KB
    __shared__ float red[4][F_OUT];
    int tid = threadIdx.x;
    for (int i = tid; i < F_OUT * W3B_STRIDE; i += 256) w3s[i] = w3b[i];
    __syncthreads();
    int half = tid >> 7;
    int t = tid & 127;
    int v = blockIdx.x * 2 + half;
    const uint4* hp = (const uint4*)h;   // row stride 128 uint4
    float sw = 1.0f / (float)(deg[v] + 1);
    float acc[8], tmp[8];
    unpack8(hp[(size_t)v * 128 + t], tmp);
#pragma unroll
    for (int j = 0; j < 8; j++) acc[j] = sw * tmp[j];
    int e = row_ptr[v], end = row_ptr[v + 1];
    for (; e + 4 <= end; e += 4) {
        int s0 = csr_src[e], s1 = csr_src[e + 1];
        int s2 = csr_src[e + 2], s3 = csr_src[e + 3];
        float w0 = csr_w[e], w1 = csr_w[e + 1];
        float w2 = csr_w[e + 2], w3 = csr_w[e + 3];
        float f0[8], f1[8], f2[8], f3[8];
        unpack8(hp[(size_t)s0 * 128 + t], f0);
        unpack8(hp[(size_t)s1 * 128 + t], f1);
        unpack8(hp[(size_t)s2 * 128 + t], f2);
        unpack8(hp[(size_t)s3 * 128 + t], f3);
#pragma unroll
        for (int j = 0; j < 8; j++)
            acc[j] += w0 * f0[j] + w1 * f1[j] + w2 * f2[j] + w3 * f3[j];
    }
    for (; e < end; e++) {
        int s = csr_src[e];
        float w = csr_w[e];
        float f0[8];
        unpack8(hp[(size_t)s * 128 + t], f0);
#pragma unroll
        for (int j = 0; j < 8; j++) acc[j] += w * f0[j];
    }
    float4 b4a = ((const float4*)b2)[t * 2];
    float4 b4b = ((const float4*)b2)[t * 2 + 1];
    acc[0] = fmaxf(acc[0] + b4a.x, 0.0f); acc[1] = fmaxf(acc[1] + b4a.y, 0.0f);
    acc[2] = fmaxf(acc[2] + b4a.z, 0.0f); acc[3] = fmaxf(acc[3] + b4a.w, 0.0f);
    acc[4] = fmaxf(acc[4] + b4b.x, 0.0f); acc[5] = fmaxf(acc[5] + b4b.y, 0.0f);
    acc[6] = fmaxf(acc[6] + b4b.z, 0.0f); acc[7] = fmaxf(acc[7] + b4b.w, 0.0f);

    float partial[F_OUT];
#pragma unroll
    for (int c = 0; c < F_OUT; c++) {
        float wf[8];
        unpack8(*(const uint4*)&w3s[c * W3B_STRIDE + t * 8], wf);
        partial[c] = acc[0] * wf[0] + acc[1] * wf[1] + acc[2] * wf[2] + acc[3] * wf[3]
                   + acc[4] * wf[4] + acc[5] * wf[5] + acc[6] * wf[6] + acc[7] * wf[7];
    }
#pragma unroll
    for (int c = 0; c < F_OUT; c++) {
#pragma unroll
        for (int off = 32; off > 0; off >>= 1)
            partial[c] += __shfl_xor(partial[c], off, 64);
    }
    int wave = tid >> 6, lane = tid & 63;
    if (lane == 0) {
#pragma unroll
        for (int c = 0; c < F_OUT; c++) red[wave][c] = partial[c];
    }
    __syncthreads();
    if (tid < 2 * F_OUT) {
        int hh = tid / F_OUT, c = tid % F_OUT;
        H3[(size_t)(blockIdx.x * 2 + hh) * H3_STRIDE + c] =
            red[hh * 2][c] + red[hh * 2 + 1][c];
    }
}

// ---------------------------------------------------------------------------
// Pipelined GEMM (T3+T4+T5): BM=128, BN=256, BK=64, 8 waves (512 thr),
// per-wave 64x64 (2x2 of 32x32x16 MFMA). 3-buffer LDS rotation (144 KB),
// counted vmcnt(6): tile t+2's loads stay in flight across the per-tile
// barrier while tile t computes. Raw s_barrier (no vmcnt(0) drain).
// R2 fixes vs R1: (a) proven supertile block mapping (same-mtile blocks on
// one XCD -> A panel L2-resident; FETCH was 2.1x without it); (b) the 6
// stage loads are spread across kk-phases (2 per phase, m201-style) to
// reduce LDS write-port pressure under concurrent ds_reads.
// ---------------------------------------------------------------------------
#define GP_STAGE_A(t_, q_) do {                                                \
    unsigned short* As_ = lds + (q_) * 24576;                                  \
    int k0_ = (t_) * 64;                                                       \
    _Pragma("unroll")                                                          \
    for (int j = 0; j < 2; j++) {           /* A: 128x64 = 1024 16B slots */   \
        int idx = j * 512 + tid;                                               \
        int r = idx >> 3;                                                      \
        int kc = (idx & 7) ^ (r & 7);                                          \
        __builtin_amdgcn_global_load_lds(                                      \
            (const __attribute__((address_space(1))) void*)(Abase + (size_t)r * K + k0_ + kc * 8), \
            (__attribute__((address_space(3))) void*)(&As_[idx * 8]), 16, 0, 0); \
    }                                                                          \
} while (0)

#define GP_STAGE_B(t_, q_, j0_) do {                                           \
    unsigned short* Bs_ = lds + (q_) * 24576 + 8192;                           \
    int k0_ = (t_) * 64;                                                       \
    _Pragma("unroll")                                                          \
    for (int j = (j0_); j < (j0_) + 2; j++) {   /* B: 256x64 = 2048 slots */   \
        int idx = j * 512 + tid;                                               \
        int r = idx >> 3;                                                      \
        int kc = (idx & 7) ^ (r & 7);                                          \
        __builtin_amdgcn_global_load_lds(                                      \
            (const __attribute__((address_space(1))) void*)(Bbase + (size_t)r * K + k0_ + kc * 8), \
            (__attribute__((address_space(3))) void*)(&Bs_[idx * 8]), 16, 0, 0); \
    }                                                                          \
} while (0)

template <bool OUT_BF16, bool BIAS, bool RELU>
__global__ __launch_bounds__(512) void gemm_pipe_kernel(
        const unsigned short* __restrict__ A,   // [M,K] bf16
        const unsigned short* __restrict__ Bt,  // [N,K] bf16
        const float* __restrict__ bias,         // [N] or null
        void* __restrict__ C,                   // [M,N] bf16 or f32
        int M, int N, int K) {
    __shared__ unsigned short lds[3 * 24576];   // 3 x (A 16KB + B 32KB) = 144 KB
    int tid = threadIdx.x;
    int wave = tid >> 6, lane = tid & 63;
    int wm = wave & 1, wn = wave >> 1;          // 2M x 4N wave grid
    int lrow = lane & 31, lhalf = lane >> 5;

    // Proven supertile mapping: same-mtile blocks share b&7 (same XCD, A
    // panel L2-resident); consecutive b>>3 walk ntiles (B panels shared
    // via L3). Identical formula to the verified 287us kernel.
    int GN = N >> 8;                            // 256-wide n-tiles
    int b = blockIdx.x;
    int ntile = (b >> 3) % GN;
    int mtile = ((b >> 3) / GN) * 8 + (b & 7);

    const unsigned short* Abase = A + (size_t)mtile * 128 * K;
    const unsigned short* Bbase = Bt + (size_t)ntile * 256 * K;

    floatx16 acc[2][2] = {};
    int NT = K >> 6;

    // Prologue: stage tiles 0 and 1; wait only for tile 0 (6 = tile 1 in flight)
    GP_STAGE_A(0, 0); GP_STAGE_B(0, 0, 0); GP_STAGE_B(0, 0, 2);
    GP_STAGE_A(1, 1); GP_STAGE_B(1, 1, 0); GP_STAGE_B(1, 1, 2);
    asm volatile("s_waitcnt vmcnt(6)" ::: "memory");
    __builtin_amdgcn_s_barrier();

    int q = 0, qn = 2;                          // current buf, (t+2)%3 buf
    for (int t = 0; t < NT; t++) {
        unsigned short* As_ = lds + q * 24576;
        unsigned short* Bs_ = As_ + 8192;
#pragma unroll
        for (int kk = 0; kk < 4; kk++) {        // 4 k16-phases
            bf16x8 af[2], bfr[2];
            int c = kk * 2 + lhalf;             // 16B chunk index 0..7
#pragma unroll
            for (int mt = 0; mt < 2; mt++) {
                int R = wm * 64 + mt * 32 + lrow;
                af[mt] = *(const bf16x8*)&As_[(R * 8 + (c ^ (R & 7))) * 8];
            }
#pragma unroll
            for (int nt = 0; nt < 2; nt++) {
                int R = wn * 64 + nt * 32 + lrow;
                bfr[nt] = *(const bf16x8*)&Bs_[(R * 8 + (c ^ (R & 7))) * 8];
            }
            // Spread the 6 prefetch loads for tile t+2 across phases 0..2
            if (t + 2 < NT) {
                if (kk == 0)      GP_STAGE_A(t + 2, qn);
                else if (kk == 1) GP_STAGE_B(t + 2, qn, 0);
                else if (kk == 2) GP_STAGE_B(t + 2, qn, 2);
            }
            __builtin_amdgcn_s_setprio(1);
#pragma unroll
            for (int mt = 0; mt < 2; mt++)
#pragma unroll
                for (int nt = 0; nt < 2; nt++)
                    acc[mt][nt] = __builtin_amdgcn_mfma_f32_32x32x16_bf16(
                        af[mt], bfr[nt], acc[mt][nt], 0, 0, 0);
            __builtin_amdgcn_s_setprio(0);
        }
        // Publish tile t+1: wait for its 6 loads only (t+2's 6 stay in flight).
        if (t + 2 < NT)
            asm volatile("s_waitcnt vmcnt(6)" ::: "memory");
        else
            asm volatile("s_waitcnt vmcnt(0)" ::: "memory");
        __builtin_amdgcn_s_barrier();
        q = (q == 2) ? 0 : q + 1;
        qn = (qn == 2) ? 0 : qn + 1;
    }

#pragma unroll
    for (int mt = 0; mt < 2; mt++) {
#pragma unroll
        for (int nt = 0; nt < 2; nt++) {
            int col = ntile * 256 + wn * 64 + nt * 32 + lrow;
            float bv = BIAS ? bias[col] : 0.0f;
#pragma unroll
            for (int reg = 0; reg < 16; reg++) {
                int row = mtile * 128 + wm * 64 + mt * 32 + (reg & 3) + 8 * (reg >> 2) + 4 * lhalf;
                float v = acc[mt][nt][reg] + bv;
                if (RELU) v = fmaxf(v, 0.0f);
                if (OUT_BF16)
                    ((unsigned short*)C)[(size_t)row * N + col] = f2bf(v);
                else
                    ((float*)C)[(size_t)row * N + col] = v;
            }
        }
    }
}

// ---------------------------------------------------------------------------
// Final: aggregate h3 (stride 16), add b3, log_softmax per node.
// ---------------------------------------------------------------------------
__global__ void final_kernel(const float* __restrict__ h3, const int* __restrict__ row_ptr,
                             const int* __restrict__ csr_src, const float* __restrict__ csr_w,
                             const int* __restrict__ deg, const float* __restrict__ b3,
                             float* __restrict__ out) {
    int v = blockIdx.x * blockDim.x + threadIdx.x;
    if (v >= N_NODES) return;
    const float4* h4 = (const float4*)h3;
    float sw = 1.0f / (float)(deg[v] + 1);
    float a[12];
    *(float4*)&a[0] = h4[v * 4];
    *(float4*)&a[4] = h4[v * 4 + 1];
    *(float4*)&a[8] = h4[v * 4 + 2];
    float acc[F_OUT];
#pragma unroll
    for (int c = 0; c < F_OUT; c++) acc[c] = b3[c] + sw * a[c];
    int end = row_ptr[v + 1];
    for (int e = row_ptr[v]; e < end; e++) {
        int s = csr_src[e];
        float w = csr_w[e];
        float bsrc[12];
        *(float4*)&bsrc[0] = h4[s * 4];
        *(float4*)&bsrc[4] = h4[s * 4 + 1];
        *(float4*)&bsrc[8] = h4[s * 4 + 2];
#pragma unroll
        for (int c = 0; c < F_OUT; c++) acc[c] += w * bsrc[c];
    }
    float m = acc[0];
#pragma unroll
    for (int c = 1; c < F_OUT; c++) m = fmaxf(m, acc[c]);
    float ssum = 0.0f;
#pragma unroll
    for (int c = 0; c < F_OUT; c++) ssum += expf(acc[c] - m);
    float l = logf(ssum);
#pragma unroll
    for (int c = 0; c < F_OUT; c++) out[v * F_OUT + c] = acc[c] - m - l;
}

// ---------------------------------------------------------------------------
// Launch (7 dispatches)
// ---------------------------------------------------------------------------
extern "C" void kernel_launch(void* const* d_in, const int* in_sizes, int n_in,
                              void* d_out, int out_size, void* d_ws, size_t ws_size,
                              hipStream_t stream) {
    const float* x  = (const float*)d_in[0];
    const float* W1 = (const float*)d_in[1];
    const float* b1 = (const float*)d_in[2];
    const float* W2 = (const float*)d_in[3];
    const float* b2 = (const float*)d_in[4];
    const float* W3 = (const float*)d_in[5];
    const float* b3 = (const float*)d_in[6];
    const int*   ei = (const int*)d_in[7];
    float* out = (float*)d_out;

    char* p = (char*)d_ws;
    int*   deg     = (int*)p;    p += N_NODES * 4;
    int*   cnt     = (int*)p;    p += N_NODES * 4;
    int*   row_ptr = (int*)p;    p += 33024;
    int*   csr_src = (int*)p;    p += N_EDGES * 4;
    float* csr_w   = (float*)p;  p += N_EDGES * 4;
    float* h3      = (float*)p;  p += N_NODES * H3_STRIDE * 4;
    unsigned short* w3b = (unsigned short*)p; p += (F_OUT * W3B_STRIDE * 2 + 255) / 256 * 256;
    unsigned short* xb    = (unsigned short*)p; p += (size_t)N_NODES * F_IN * 2;
    unsigned short* agg_x = (unsigned short*)p; p += (size_t)N_NODES * F_IN * 2;
    unsigned short* W1t   = (unsigned short*)p; p += (size_t)HID1 * F_IN * 2;
    unsigned short* W2t   = (unsigned short*)p; p += (size_t)HID2 * HID1 * 2;
    unsigned short* h1    = (unsigned short*)p; p += (size_t)N_NODES * HID1 * 2;
    unsigned short* h2pre = (unsigned short*)p; p += (size_t)N_NODES * HID2 * 2;

    // Graph preprocessing + all conversions (2 launches)
    hist_scan_kernel<<<1, 1024, 0, stream>>>(ei, deg, row_ptr, cnt);
    megaprep_kernel<<<10497, 256, 0, stream>>>(ei, deg, row_ptr, cnt, csr_src, csr_w,
                                               x, xb, W1, W1t, W2, W2t, W3, w3b);

    // Layer 1
    agg1_kernel<<<N_NODES / 4, 256, 0, stream>>>(xb, row_ptr, csr_src, csr_w, deg, agg_x);
    gemm_pipe_kernel<true, true, true><<<(N_NODES / 128) * (HID1 / 256), 512, 0, stream>>>(
        agg_x, W1t, b1, h1, N_NODES, HID1, F_IN);

    // Layer 2 (pipelined: counted vmcnt, 3-buffer LDS)
    gemm_pipe_kernel<true, false, false><<<(N_NODES / 128) * (HID2 / 256), 512, 0, stream>>>(
        h1, W2t, nullptr, h2pre, N_NODES, HID2, HID1);

    // Layer 2 aggregation + Layer 3 GEMM fused
    agg2_gemm3_kernel<<<N_NODES / 2, 256, 0, stream>>>(h2pre, row_ptr, csr_src, csr_w,
                                                       deg, b2, w3b, h3);

    // Output
    final_kernel<<<N_NODES / 256, 256, 0, stream>>>(h3, row_ptr, csr_src, csr_w, deg, b3, out);
}

// Round 3
// 284.121 us; speedup vs baseline: 1.0477x; 1.0316x over previous
//
#include <hip/hip_runtime.h>
#include <math.h>

#define N_NODES 8192
#define N_EDGES 65536
#define F_IN    512
#define HID1    4096
#define HID2    1024
#define F_OUT   10
#define H3_STRIDE 16
#define W3B_STRIDE 1032   // padded K-stride of bf16 W3^T rows

typedef __bf16 bf16x8 __attribute__((ext_vector_type(8)));
typedef float floatx4 __attribute__((ext_vector_type(4)));
typedef float floatx16 __attribute__((ext_vector_type(16)));

static __device__ __forceinline__ unsigned short f2bf(float f) {
    union { float f; unsigned u; } v; v.f = f;
    unsigned r = v.u + 0x7fffu + ((v.u >> 16) & 1u);   // RNE
    return (unsigned short)(r >> 16);
}
static __device__ __forceinline__ float bf2f(unsigned short u) {
    union { unsigned u; float f; } v; v.u = ((unsigned)u) << 16;
    return v.f;
}
static __device__ __forceinline__ void unpack8(uint4 r, float* f) {
    union { unsigned u; float v; } c;
    c.u = r.x << 16;          f[0] = c.v;
    c.u = r.x & 0xffff0000u;  f[1] = c.v;
    c.u = r.y << 16;          f[2] = c.v;
    c.u = r.y & 0xffff0000u;  f[3] = c.v;
    c.u = r.z << 16;          f[4] = c.v;
    c.u = r.z & 0xffff0000u;  f[5] = c.v;
    c.u = r.w << 16;          f[6] = c.v;
    c.u = r.w & 0xffff0000u;  f[7] = c.v;
}
static __device__ __forceinline__ uint4 pack8(const float* f) {
    uint4 o;
    o.x = (unsigned)f2bf(f[0]) | ((unsigned)f2bf(f[1]) << 16);
    o.y = (unsigned)f2bf(f[2]) | ((unsigned)f2bf(f[3]) << 16);
    o.z = (unsigned)f2bf(f[4]) | ((unsigned)f2bf(f[5]) << 16);
    o.w = (unsigned)f2bf(f[6]) | ((unsigned)f2bf(f[7]) << 16);
    return o;
}

// ---------------------------------------------------------------------------
// hist+scan (one block): deg[] via LDS histogram, exclusive scan -> row_ptr,
// cnt[] zeroing.
// ---------------------------------------------------------------------------
__global__ __launch_bounds__(1024) void hist_scan_kernel(
        const int* __restrict__ ei, int* __restrict__ deg,
        int* __restrict__ row_ptr, int* __restrict__ cnt) {
    __shared__ int hist[N_NODES];        // 32 KB
    __shared__ int sums[1024];
    int t = threadIdx.x;
#pragma unroll
    for (int i = 0; i < 8; i++) hist[t + i * 1024] = 0;
    __syncthreads();
#pragma unroll
    for (int i = 0; i < 64; i++) {
        int d = ei[N_EDGES + i * 1024 + t];
        atomicAdd(&hist[d], 1);
    }
    __syncthreads();
    int base = t * 8;
    int local[8], run = 0;
#pragma unroll
    for (int i = 0; i < 8; i++) {
        int dv = hist[base + i];
        deg[base + i] = dv;
        cnt[base + i] = 0;
        local[i] = run; run += dv;
    }
    sums[t] = run;
    __syncthreads();
    for (int off = 1; off < 1024; off <<= 1) {
        int val = (t >= off) ? sums[t - off] : 0;
        __syncthreads();
        sums[t] += val;
        __syncthreads();
    }
    int offset = (t == 0) ? 0 : sums[t - 1];
#pragma unroll
    for (int i = 0; i < 8; i++) row_ptr[base + i] = offset + local[i];
    if (t == 1023) row_ptr[N_NODES] = sums[1023];
}

// ---------------------------------------------------------------------------
// megaprep: fill CSR (blocks 0..255) + xcvt (256..4351) + W1^T (4352..6399)
// + W2^T (6400..10495) + W3 bf16 cvt (10496). One launch.
// ---------------------------------------------------------------------------
static __device__ __forceinline__ void transpose_body(
        const float* __restrict__ W, unsigned short* __restrict__ Wt,
        int K, int N, int k0, int n0, int tid, float (*t)[33]) {
    int c = tid & 31, r8 = tid >> 5;
#pragma unroll
    for (int i = 0; i < 4; i++) {
        int r = r8 + i * 8;
        t[r][c] = W[(size_t)(k0 + r) * N + n0 + c];
    }
    __syncthreads();
#pragma unroll
    for (int i = 0; i < 4; i++) {
        int r = r8 + i * 8;
        Wt[(size_t)(n0 + r) * K + k0 + c] = f2bf(t[c][r]);
    }
}

__global__ __launch_bounds__(256) void megaprep_kernel(
        const int* __restrict__ ei, const int* __restrict__ deg,
        const int* __restrict__ row_ptr, int* __restrict__ cnt,
        int* __restrict__ csr_src, float* __restrict__ csr_w,
        const float* __restrict__ x, unsigned short* __restrict__ xb,
        const float* __restrict__ W1, unsigned short* __restrict__ W1t,
        const float* __restrict__ W2, unsigned short* __restrict__ W2t,
        const float* __restrict__ W3, unsigned short* __restrict__ w3b) {
    __shared__ float t[32][33];
    int b = blockIdx.x, tid = threadIdx.x;
    if (b < 256) {
        int e = b * 256 + tid;
        int s = ei[e];
        int d = ei[N_EDGES + e];
        int slot = row_ptr[d] + atomicAdd(&cnt[d], 1);
        csr_src[slot] = s;
        csr_w[slot] = rsqrtf((float)((deg[s] + 1) * (deg[d] + 1)));
    } else if (b < 4352) {
        int i = (b - 256) * 256 + tid;
        float4 a = ((const float4*)x)[i];
        ushort4 o;
        o.x = f2bf(a.x); o.y = f2bf(a.y); o.z = f2bf(a.z); o.w = f2bf(a.w);
        ((ushort4*)xb)[i] = o;
    } else if (b < 6400) {
        int bb = b - 4352;                       // W1: K=512, N=4096
        transpose_body(W1, W1t, F_IN, HID1, (bb >> 7) * 32, (bb & 127) * 32, tid, t);
    } else if (b < 10496) {
        int bb = b - 6400;                       // W2: K=4096, N=1024
        transpose_body(W2, W2t, HID1, HID2, (bb >> 5) * 32, (bb & 31) * 32, tid, t);
    } else {
        // W3 [1024,10] f32 -> w3b [10][W3B_STRIDE] bf16 (transposed)
        for (int i = tid; i < HID2 * F_OUT; i += 256) {
            int k = i / F_OUT, c = i % F_OUT;
            w3b[c * W3B_STRIDE + k] = f2bf(W3[i]);
        }
    }
}

// ---------------------------------------------------------------------------
// agg1: agg_x[v,:] = sum_e w_e*xb[src,:] + xb[v,:]/(deg+1) -> bf16
// 1 node per wave (64 lanes x uint4 = 1 KB row), 4 nodes/block. Unroll x4.
// ---------------------------------------------------------------------------
__global__ __launch_bounds__(256) void agg1_kernel(
        const unsigned short* __restrict__ xb, const int* __restrict__ row_ptr,
        const int* __restrict__ csr_src, const float* __restrict__ csr_w,
        const int* __restrict__ deg, unsigned short* __restrict__ out) {
    int v = blockIdx.x * 4 + (threadIdx.x >> 6);
    int t = threadIdx.x & 63;
    const uint4* xp = (const uint4*)xb;        // row stride 64 uint4
    float sw = 1.0f / (float)(deg[v] + 1);
    float acc[8], tmp[8];
    unpack8(xp[(size_t)v * 64 + t], tmp);
#pragma unroll
    for (int j = 0; j < 8; j++) acc[j] = sw * tmp[j];
    int e = row_ptr[v], end = row_ptr[v + 1];
    for (; e + 4 <= end; e += 4) {
        int s0 = csr_src[e], s1 = csr_src[e + 1];
        int s2 = csr_src[e + 2], s3 = csr_src[e + 3];
        float w0 = csr_w[e], w1 = csr_w[e + 1];
        float w2 = csr_w[e + 2], w3 = csr_w[e + 3];
        float f0[8], f1[8], f2[8], f3[8];
        unpack8(xp[(size_t)s0 * 64 + t], f0);
        unpack8(xp[(size_t)s1 * 64 + t], f1);
        unpack8(xp[(size_t)s2 * 64 + t], f2);
        unpack8(xp[(size_t)s3 * 64 + t], f3);
#pragma unroll
        for (int j = 0; j < 8; j++)
            acc[j] += w0 * f0[j] + w1 * f1[j] + w2 * f2[j] + w3 * f3[j];
    }
    for (; e < end; e++) {
        int s = csr_src[e];
        float w = csr_w[e];
        float f0[8];
        unpack8(xp[(size_t)s * 64 + t], f0);
#pragma unroll
        for (int j = 0; j < 8; j++) acc[j] += w * f0[j];
    }
    ((uint4*)out)[(size_t)v * 64 + t] = pack8(acc);
}

// ---------------------------------------------------------------------------
// agg2 + gemm3 fused. Unroll x4 on the edge loop.
// ---------------------------------------------------------------------------
__global__ __launch_bounds__(256) void agg2_gemm3_kernel(
        const unsigned short* __restrict__ h, const int* __restrict__ row_ptr,
        const int* __restrict__ csr_src, const float* __restrict__ csr_w,
        const int* __restrict__ deg, const float* __restrict__ b2,
        const unsigned short* __restrict__ w3b, float* __restrict__ H3) {
    __shared__ unsigned short w3s[F_OUT * W3B_STRIDE];   // ~20.2 KB
    __shared__ float red[4][F_OUT];
    int tid = threadIdx.x;
    for (int i = tid; i < F_OUT * W3B_STRIDE; i += 256) w3s[i] = w3b[i];
    __syncthreads();
    int half = tid >> 7;
    int t = tid & 127;
    int v = blockIdx.x * 2 + half;
    const uint4* hp = (const uint4*)h;   // row stride 128 uint4
    float sw = 1.0f / (float)(deg[v] + 1);
    float acc[8], tmp[8];
    unpack8(hp[(size_t)v * 128 + t], tmp);
#pragma unroll
    for (int j = 0; j < 8; j++) acc[j] = sw * tmp[j];
    int e = row_ptr[v], end = row_ptr[v + 1];
    for (; e + 4 <= end; e += 4) {
        int s0 = csr_src[e], s1 = csr_src[e + 1];
        int s2 = csr_src[e + 2], s3 = csr_src[e + 3];
        float w0 = csr_w[e], w1 = csr_w[e + 1];
        float w2 = csr_w[e + 2], w3 = csr_w[e + 3];
        float f0[8], f1[8], f2[8], f3[8];
        unpack8(hp[(size_t)s0 * 128 + t], f0);
        unpack8(hp[(size_t)s1 * 128 + t], f1);
        unpack8(hp[(size_t)s2 * 128 + t], f2);
        unpack8(hp[(size_t)s3 * 128 + t], f3);
#pragma unroll
        for (int j = 0; j < 8; j++)
            acc[j] += w0 * f0[j] + w1 * f1[j] + w2 * f2[j] + w3 * f3[j];
    }
    for (; e < end; e++) {
        int s = csr_src[e];
        float w = csr_w[e];
        float f0[8];
        unpack8(hp[(size_t)s * 128 + t], f0);
#pragma unroll
        for (int j = 0; j < 8; j++) acc[j] += w * f0[j];
    }
    float4 b4a = ((const float4*)b2)[t * 2];
    float4 b4b = ((const float4*)b2)[t * 2 + 1];
    acc[0] = fmaxf(acc[0] + b4a.x, 0.0f); acc[1] = fmaxf(acc[1] + b4a.y, 0.0f);
    acc[2] = fmaxf(acc[2] + b4a.z, 0.0f); acc[3] = fmaxf(acc[3] + b4a.w, 0.0f);
    acc[4] = fmaxf(acc[4] + b4b.x, 0.0f); acc[5] = fmaxf(acc[5] + b4b.y, 0.0f);
    acc[6] = fmaxf(acc[6] + b4b.z, 0.0f); acc[7] = fmaxf(acc[7] + b4b.w, 0.0f);

    float partial[F_OUT];
#pragma unroll
    for (int c = 0; c < F_OUT; c++) {
        float wf[8];
        unpack8(*(const uint4*)&w3s[c * W3B_STRIDE + t * 8], wf);
        partial[c] = acc[0] * wf[0] + acc[1] * wf[1] + acc[2] * wf[2] + acc[3] * wf[3]
                   + acc[4] * wf[4] + acc[5] * wf[5] + acc[6] * wf[6] + acc[7] * wf[7];
    }
#pragma unroll
    for (int c = 0; c < F_OUT; c++) {
#pragma unroll
        for (int off = 32; off > 0; off >>= 1)
            partial[c] += __shfl_xor(partial[c], off, 64);
    }
    int wave = tid >> 6, lane = tid & 63;
    if (lane == 0) {
#pragma unroll
        for (int c = 0; c < F_OUT; c++) red[wave][c] = partial[c];
    }
    __syncthreads();
    if (tid < 2 * F_OUT) {
        int hh = tid / F_OUT, c = tid % F_OUT;
        H3[(size_t)(blockIdx.x * 2 + hh) * H3_STRIDE + c] =
            red[hh * 2][c] + red[hh * 2 + 1][c];
    }
}

// ---------------------------------------------------------------------------
// GEMM2 (R3): BM=256, BN=128, BK=64, 4 waves (2Mx2N), wave-tile 128x64
// (acc[4][2]) -- the original gemm1's PROVEN wave-tiling (42.7 FLOP per LDS
// byte vs 32 for 64x64 wave-tiles; LDS-read no longer the critical pipe) --
// plus the 3-buffer counted-vmcnt pipeline (12 loads/thread/tile, vmcnt(12),
// never drained in the main loop). Grid 32x8=256 = 1 block/CU, LDS 144 KB.
// ---------------------------------------------------------------------------
#define G2_STAGE_A(t_, q_, j0_) do {                                           \
    unsigned short* As_ = lds + (q_) * 24576;                                  \
    int k0_ = (t_) * 64;                                                       \
    _Pragma("unroll")                                                          \
    for (int j = (j0_); j < (j0_) + 4; j++) {   /* A: 256x64 = 2048 slots */   \
        int idx = j * 256 + tid;                                               \
        int r = idx >> 3;                                                      \
        int kc = (idx & 7) ^ (r & 7);                                          \
        __builtin_amdgcn_global_load_lds(                                      \
            (const __attribute__((address_space(1))) void*)(Abase + (size_t)r * K + k0_ + kc * 8), \
            (__attribute__((address_space(3))) void*)(&As_[idx * 8]), 16, 0, 0); \
    }                                                                          \
} while (0)

#define G2_STAGE_B(t_, q_) do {                                                \
    unsigned short* Bs_ = lds + (q_) * 24576 + 16384;                          \
    int k0_ = (t_) * 64;                                                       \
    _Pragma("unroll")                                                          \
    for (int j = 0; j < 4; j++) {               /* B: 128x64 = 1024 slots */   \
        int idx = j * 256 + tid;                                               \
        int r = idx >> 3;                                                      \
        int kc = (idx & 7) ^ (r & 7);                                          \
        __builtin_amdgcn_global_load_lds(                                      \
            (const __attribute__((address_space(1))) void*)(Bbase + (size_t)r * K + k0_ + kc * 8), \
            (__attribute__((address_space(3))) void*)(&Bs_[idx * 8]), 16, 0, 0); \
    }                                                                          \
} while (0)

template <bool OUT_BF16, bool BIAS, bool RELU>
__global__ __launch_bounds__(256, 1) void gemm2_pipe_kernel(
        const unsigned short* __restrict__ A,   // [M,K] bf16
        const unsigned short* __restrict__ Bt,  // [N,K] bf16
        const float* __restrict__ bias,         // [N] or null
        void* __restrict__ C,                   // [M,N] bf16 or f32
        int M, int N, int K) {
    __shared__ unsigned short lds[3 * 24576];   // 3 x (A 32KB + B 16KB) = 144 KB
    int tid = threadIdx.x;
    int wave = tid >> 6, lane = tid & 63;
    int wm = wave >> 1, wn = wave & 1;          // 2x2 waves, wave-tile 128x64
    int lrow = lane & 31, lhalf = lane >> 5;

    // Proven supertile mapping (same formula as the 287us kernels).
    int GN = N >> 7;                            // 128-wide n-tiles
    int b = blockIdx.x;
    int ntile = (b >> 3) % GN;
    int mtile = ((b >> 3) / GN) * 8 + (b & 7);
    int m0 = mtile * 256, n0 = ntile * 128;

    const unsigned short* Abase = A + (size_t)m0 * K;
    const unsigned short* Bbase = Bt + (size_t)n0 * K;

    floatx16 acc[4][2] = {};
    int NT = K >> 6;

    // Prologue: stage tiles 0 and 1; wait for tile 0 (tile 1's 12 in flight)
    G2_STAGE_A(0, 0, 0); G2_STAGE_A(0, 0, 4); G2_STAGE_B(0, 0);
    G2_STAGE_A(1, 1, 0); G2_STAGE_A(1, 1, 4); G2_STAGE_B(1, 1);
    asm volatile("s_waitcnt vmcnt(12)" ::: "memory");
    __builtin_amdgcn_s_barrier();

    int q = 0, qn = 2;                          // current buf, (t+2)%3 buf
    for (int t = 0; t < NT; t++) {
        unsigned short* As_ = lds + q * 24576;
        unsigned short* Bs_ = As_ + 16384;
#pragma unroll
        for (int kk = 0; kk < 4; kk++) {        // 4 k16-phases
            bf16x8 af[4], bfr[2];
            int c = kk * 2 + lhalf;             // 16B chunk index 0..7
#pragma unroll
            for (int mt = 0; mt < 4; mt++) {
                int R = wm * 128 + mt * 32 + lrow;
                af[mt] = *(const bf16x8*)&As_[(R * 8 + (c ^ (R & 7))) * 8];
            }
#pragma unroll
            for (int nt = 0; nt < 2; nt++) {
                int R = wn * 64 + nt * 32 + lrow;
                bfr[nt] = *(const bf16x8*)&Bs_[(R * 8 + (c ^ (R & 7))) * 8];
            }
            // Spread tile t+2's 12 prefetch loads across phases 0..2
            if (t + 2 < NT) {
                if (kk == 0)      G2_STAGE_A(t + 2, qn, 0);
                else if (kk == 1) G2_STAGE_A(t + 2, qn, 4);
                else if (kk == 2) G2_STAGE_B(t + 2, qn);
            }
            __builtin_amdgcn_s_setprio(1);
#pragma unroll
            for (int mt = 0; mt < 4; mt++)
#pragma unroll
                for (int nt = 0; nt < 2; nt++)
                    acc[mt][nt] = __builtin_amdgcn_mfma_f32_32x32x16_bf16(
                        af[mt], bfr[nt], acc[mt][nt], 0, 0, 0);
            __builtin_amdgcn_s_setprio(0);
        }
        // Publish tile t+1: wait its 12 loads only (t+2's 12 stay in flight).
        if (t + 2 < NT)
            asm volatile("s_waitcnt vmcnt(12)" ::: "memory");
        else
            asm volatile("s_waitcnt vmcnt(0)" ::: "memory");
        __builtin_amdgcn_s_barrier();
        q = (q == 2) ? 0 : q + 1;
        qn = (qn == 2) ? 0 : qn + 1;
    }

#pragma unroll
    for (int mt = 0; mt < 4; mt++) {
#pragma unroll
        for (int nt = 0; nt < 2; nt++) {
            int col = n0 + wn * 64 + nt * 32 + lrow;
            float bv = BIAS ? bias[col] : 0.0f;
#pragma unroll
            for (int reg = 0; reg < 16; reg++) {
                int row = m0 + wm * 128 + mt * 32 + (reg & 3) + 8 * (reg >> 2) + 4 * lhalf;
                float v = acc[mt][nt][reg] + bv;
                if (RELU) v = fmaxf(v, 0.0f);
                if (OUT_BF16)
                    ((unsigned short*)C)[(size_t)row * N + col] = f2bf(v);
                else
                    ((float*)C)[(size_t)row * N + col] = v;
            }
        }
    }
}

// ---------------------------------------------------------------------------
// GEMM1: 256x128 tile, BK=64, 32x32x16 MFMA (verbatim proven kernel).
// ---------------------------------------------------------------------------
__global__ __launch_bounds__(256, 2) void gemm1_mfma_kernel(
        const unsigned short* __restrict__ A,   // [8192,512] bf16
        const unsigned short* __restrict__ Bt,  // [4096,512] bf16
        const float* __restrict__ bias,         // [4096]
        unsigned short* __restrict__ C) {       // [8192,4096] bf16
    __shared__ unsigned short As[256 * 64];     // 32 KB
    __shared__ unsigned short Bs[128 * 64];     // 16 KB
    const int K = F_IN, N = HID1;
    int tid = threadIdx.x;
    int wave = tid >> 6, lane = tid & 63;
    int wm = wave >> 1, wn = wave & 1;          // 2x2 waves, wave-tile 128x64
    int b = blockIdx.x;
    int GN = N >> 7;                            // 32 n-tiles
    int ntile = (b >> 3) % GN;
    int mtile = ((b >> 3) / GN) * 8 + (b & 7);  // 0..31
    int m0 = mtile * 256, n0 = ntile * 128;
    int lrow = lane & 31, lhalf = lane >> 5;

    floatx16 acc[4][2] = {};

    for (int k0 = 0; k0 < K; k0 += 64) {
#pragma unroll
        for (int j = 0; j < 8; j++) {           // A: 2048 slots
            int idx = j * 256 + tid;
            int r = idx >> 3;                   // 0..255
            int kc = (idx & 7) ^ (r & 7);
            __builtin_amdgcn_global_load_lds(
                (const __attribute__((address_space(1))) void*)(A + (size_t)(m0 + r) * K + k0 + kc * 8),
                (__attribute__((address_space(3))) void*)(&As[idx * 8]), 16, 0, 0);
        }
#pragma unroll
        for (int j = 0; j < 4; j++) {           // B: 1024 slots
            int idx = j * 256 + tid;
            int r = idx >> 3;                   // 0..127
            int kc = (idx & 7) ^ (r & 7);
            __builtin_amdgcn_global_load_lds(
                (const __attribute__((address_space(1))) void*)(Bt + (size_t)(n0 + r) * K + k0 + kc * 8),
                (__attribute__((address_space(3))) void*)(&Bs[idx * 8]), 16, 0, 0);
        }
        __syncthreads();
#pragma unroll
        for (int kk = 0; kk < 4; kk++) {
            bf16x8 af[4], bfr[2];
            int c = kk * 2 + lhalf;
#pragma unroll
            for (int mt = 0; mt < 4; mt++) {
                int R = wm * 128 + mt * 32 + lrow;
                af[mt] = *(const bf16x8*)&As[(R * 8 + (c ^ (R & 7))) * 8];
            }
#pragma unroll
            for (int nt = 0; nt < 2; nt++) {
                int R = wn * 64 + nt * 32 + lrow;
                bfr[nt] = *(const bf16x8*)&Bs[(R * 8 + (c ^ (R & 7))) * 8];
            }
#pragma unroll
            for (int mt = 0; mt < 4; mt++)
#pragma unroll
                for (int nt = 0; nt < 2; nt++)
                    acc[mt][nt] = __builtin_amdgcn_mfma_f32_32x32x16_bf16(
                        af[mt], bfr[nt], acc[mt][nt], 0, 0, 0);
        }
        __syncthreads();
    }

#pragma unroll
    for (int mt = 0; mt < 4; mt++) {
#pragma unroll
        for (int nt = 0; nt < 2; nt++) {
            int col = n0 + wn * 64 + nt * 32 + lrow;
            float bv = bias[col];
#pragma unroll
            for (int reg = 0; reg < 16; reg++) {
                int row = m0 + wm * 128 + mt * 32 + (reg & 3) + 8 * (reg >> 2) + 4 * lhalf;
                float v = fmaxf(acc[mt][nt][reg] + bv, 0.0f);
                C[(size_t)row * N + col] = f2bf(v);
            }
        }
    }
}

// ---------------------------------------------------------------------------
// Final: aggregate h3 (stride 16), add b3, log_softmax per node.
// ---------------------------------------------------------------------------
__global__ void final_kernel(const float* __restrict__ h3, const int* __restrict__ row_ptr,
                             const int* __restrict__ csr_src, const float* __restrict__ csr_w,
                             const int* __restrict__ deg, const float* __restrict__ b3,
                             float* __restrict__ out) {
    int v = blockIdx.x * blockDim.x + threadIdx.x;
    if (v >= N_NODES) return;
    const float4* h4 = (const float4*)h3;
    float sw = 1.0f / (float)(deg[v] + 1);
    float a[12];
    *(float4*)&a[0] = h4[v * 4];
    *(float4*)&a[4] = h4[v * 4 + 1];
    *(float4*)&a[8] = h4[v * 4 + 2];
    float acc[F_OUT];
#pragma unroll
    for (int c = 0; c < F_OUT; c++) acc[c] = b3[c] + sw * a[c];
    int end = row_ptr[v + 1];
    for (int e = row_ptr[v]; e < end; e++) {
        int s = csr_src[e];
        float w = csr_w[e];
        float bsrc[12];
        *(float4*)&bsrc[0] = h4[s * 4];
        *(float4*)&bsrc[4] = h4[s * 4 + 1];
        *(float4*)&bsrc[8] = h4[s * 4 + 2];
#pragma unroll
        for (int c = 0; c < F_OUT; c++) acc[c] += w * bsrc[c];
    }
    float m = acc[0];
#pragma unroll
    for (int c = 1; c < F_OUT; c++) m = fmaxf(m, acc[c]);
    float ssum = 0.0f;
#pragma unroll
    for (int c = 0; c < F_OUT; c++) ssum += expf(acc[c] - m);
    float l = logf(ssum);
#pragma unroll
    for (int c = 0; c < F_OUT; c++) out[v * F_OUT + c] = acc[c] - m - l;
}

// ---------------------------------------------------------------------------
// Launch (7 dispatches)
// ---------------------------------------------------------------------------
extern "C" void kernel_launch(void* const* d_in, const int* in_sizes, int n_in,
                              void* d_out, int out_size, void* d_ws, size_t ws_size,
                              hipStream_t stream) {
    const float* x  = (const float*)d_in[0];
    const float* W1 = (const float*)d_in[1];
    const float* b1 = (const float*)d_in[2];
    const float* W2 = (const float*)d_in[3];
    const float* b2 = (const float*)d_in[4];
    const float* W3 = (const float*)d_in[5];
    const float* b3 = (const float*)d_in[6];
    const int*   ei = (const int*)d_in[7];
    float* out = (float*)d_out;

    char* p = (char*)d_ws;
    int*   deg     = (int*)p;    p += N_NODES * 4;
    int*   cnt     = (int*)p;    p += N_NODES * 4;
    int*   row_ptr = (int*)p;    p += 33024;
    int*   csr_src = (int*)p;    p += N_EDGES * 4;
    float* csr_w   = (float*)p;  p += N_EDGES * 4;
    float* h3      = (float*)p;  p += N_NODES * H3_STRIDE * 4;
    unsigned short* w3b = (unsigned short*)p; p += (F_OUT * W3B_STRIDE * 2 + 255) / 256 * 256;
    unsigned short* xb    = (unsigned short*)p; p += (size_t)N_NODES * F_IN * 2;
    unsigned short* agg_x = (unsigned short*)p; p += (size_t)N_NODES * F_IN * 2;
    unsigned short* W1t   = (unsigned short*)p; p += (size_t)HID1 * F_IN * 2;
    unsigned short* W2t   = (unsigned short*)p; p += (size_t)HID2 * HID1 * 2;
    unsigned short* h1    = (unsigned short*)p; p += (size_t)N_NODES * HID1 * 2;
    unsigned short* h2pre = (unsigned short*)p; p += (size_t)N_NODES * HID2 * 2;

    // Graph preprocessing + all conversions (2 launches)
    hist_scan_kernel<<<1, 1024, 0, stream>>>(ei, deg, row_ptr, cnt);
    megaprep_kernel<<<10497, 256, 0, stream>>>(ei, deg, row_ptr, cnt, csr_src, csr_w,
                                               x, xb, W1, W1t, W2, W2t, W3, w3b);

    // Layer 1
    agg1_kernel<<<N_NODES / 4, 256, 0, stream>>>(xb, row_ptr, csr_src, csr_w, deg, agg_x);
    gemm1_mfma_kernel<<<(HID1 / 128) * (N_NODES / 256), 256, 0, stream>>>(agg_x, W1t, b1, h1);

    // Layer 2: 128x64 wave-tiles + 3-buffer counted-vmcnt pipeline
    gemm2_pipe_kernel<true, false, false><<<(N_NODES / 256) * (HID2 / 128), 256, 0, stream>>>(
        h1, W2t, nullptr, h2pre, N_NODES, HID2, HID1);

    // Layer 2 aggregation + Layer 3 GEMM fused
    agg2_gemm3_kernel<<<N_NODES / 2, 256, 0, stream>>>(h2pre, row_ptr, csr_src, csr_w,
                                                       deg, b2, w3b, h3);

    // Output
    final_kernel<<<N_NODES / 256, 256, 0, stream>>>(h3, row_ptr, csr_src, csr_w, deg, b3, out);
}

// Round 4
// 284.044 us; speedup vs baseline: 1.0480x; 1.0003x over previous
//
#include <hip/hip_runtime.h>
#include <math.h>

#define N_NODES 8192
#define N_EDGES 65536
#define F_IN    512
#define HID1    4096
#define HID2    1024
#define F_OUT   10
#define H3_STRIDE 16
#define W3B_STRIDE 1032   // padded K-stride of bf16 W3^T rows

typedef __bf16 bf16x8 __attribute__((ext_vector_type(8)));
typedef float floatx4 __attribute__((ext_vector_type(4)));
typedef float floatx16 __attribute__((ext_vector_type(16)));

static __device__ __forceinline__ unsigned short f2bf(float f) {
    union { float f; unsigned u; } v; v.f = f;
    unsigned r = v.u + 0x7fffu + ((v.u >> 16) & 1u);   // RNE
    return (unsigned short)(r >> 16);
}
static __device__ __forceinline__ float bf2f(unsigned short u) {
    union { unsigned u; float f; } v; v.u = ((unsigned)u) << 16;
    return v.f;
}
static __device__ __forceinline__ void unpack8(uint4 r, float* f) {
    union { unsigned u; float v; } c;
    c.u = r.x << 16;          f[0] = c.v;
    c.u = r.x & 0xffff0000u;  f[1] = c.v;
    c.u = r.y << 16;          f[2] = c.v;
    c.u = r.y & 0xffff0000u;  f[3] = c.v;
    c.u = r.z << 16;          f[4] = c.v;
    c.u = r.z & 0xffff0000u;  f[5] = c.v;
    c.u = r.w << 16;          f[6] = c.v;
    c.u = r.w & 0xffff0000u;  f[7] = c.v;
}
static __device__ __forceinline__ uint4 pack8(const float* f) {
    uint4 o;
    o.x = (unsigned)f2bf(f[0]) | ((unsigned)f2bf(f[1]) << 16);
    o.y = (unsigned)f2bf(f[2]) | ((unsigned)f2bf(f[3]) << 16);
    o.z = (unsigned)f2bf(f[4]) | ((unsigned)f2bf(f[5]) << 16);
    o.w = (unsigned)f2bf(f[6]) | ((unsigned)f2bf(f[7]) << 16);
    return o;
}

// ---------------------------------------------------------------------------
// hist+scan (one block): deg[] via LDS histogram (int4-vectorized loads),
// exclusive scan -> row_ptr, cnt[] zeroing.
// ---------------------------------------------------------------------------
__global__ __launch_bounds__(1024) void hist_scan_kernel(
        const int* __restrict__ ei, int* __restrict__ deg,
        int* __restrict__ row_ptr, int* __restrict__ cnt) {
    __shared__ int hist[N_NODES];        // 32 KB
    __shared__ int sums[1024];
    int t = threadIdx.x;
#pragma unroll
    for (int i = 0; i < 8; i++) hist[t + i * 1024] = 0;
    __syncthreads();
    const int4* ei4 = (const int4*)(ei + N_EDGES);
#pragma unroll
    for (int i = 0; i < 16; i++) {
        int4 d4 = ei4[i * 1024 + t];
        atomicAdd(&hist[d4.x], 1);
        atomicAdd(&hist[d4.y], 1);
        atomicAdd(&hist[d4.z], 1);
        atomicAdd(&hist[d4.w], 1);
    }
    __syncthreads();
    int base = t * 8;
    int local[8], run = 0;
#pragma unroll
    for (int i = 0; i < 8; i++) {
        int dv = hist[base + i];
        deg[base + i] = dv;
        cnt[base + i] = 0;
        local[i] = run; run += dv;
    }
    sums[t] = run;
    __syncthreads();
    for (int off = 1; off < 1024; off <<= 1) {
        int val = (t >= off) ? sums[t - off] : 0;
        __syncthreads();
        sums[t] += val;
        __syncthreads();
    }
    int offset = (t == 0) ? 0 : sums[t - 1];
#pragma unroll
    for (int i = 0; i < 8; i++) row_ptr[base + i] = offset + local[i];
    if (t == 1023) row_ptr[N_NODES] = sums[1023];
}

// ---------------------------------------------------------------------------
// megaprep: fill CSR (blocks 0..255) + xcvt (256..4351) + W1^T (4352..6399)
// + W2^T (6400..10495) + W3 bf16 cvt (10496). One launch.
// ---------------------------------------------------------------------------
static __device__ __forceinline__ void transpose_body(
        const float* __restrict__ W, unsigned short* __restrict__ Wt,
        int K, int N, int k0, int n0, int tid, float (*t)[33]) {
    int c = tid & 31, r8 = tid >> 5;
#pragma unroll
    for (int i = 0; i < 4; i++) {
        int r = r8 + i * 8;
        t[r][c] = W[(size_t)(k0 + r) * N + n0 + c];
    }
    __syncthreads();
#pragma unroll
    for (int i = 0; i < 4; i++) {
        int r = r8 + i * 8;
        Wt[(size_t)(n0 + r) * K + k0 + c] = f2bf(t[c][r]);
    }
}

__global__ __launch_bounds__(256) void megaprep_kernel(
        const int* __restrict__ ei, const int* __restrict__ deg,
        const int* __restrict__ row_ptr, int* __restrict__ cnt,
        int* __restrict__ csr_src, float* __restrict__ csr_w,
        const float* __restrict__ x, unsigned short* __restrict__ xb,
        const float* __restrict__ W1, unsigned short* __restrict__ W1t,
        const float* __restrict__ W2, unsigned short* __restrict__ W2t,
        const float* __restrict__ W3, unsigned short* __restrict__ w3b) {
    __shared__ float t[32][33];
    int b = blockIdx.x, tid = threadIdx.x;
    if (b < 256) {
        int e = b * 256 + tid;
        int s = ei[e];
        int d = ei[N_EDGES + e];
        int slot = row_ptr[d] + atomicAdd(&cnt[d], 1);
        csr_src[slot] = s;
        csr_w[slot] = rsqrtf((float)((deg[s] + 1) * (deg[d] + 1)));
    } else if (b < 4352) {
        int i = (b - 256) * 256 + tid;
        float4 a = ((const float4*)x)[i];
        ushort4 o;
        o.x = f2bf(a.x); o.y = f2bf(a.y); o.z = f2bf(a.z); o.w = f2bf(a.w);
        ((ushort4*)xb)[i] = o;
    } else if (b < 6400) {
        int bb = b - 4352;                       // W1: K=512, N=4096
        transpose_body(W1, W1t, F_IN, HID1, (bb >> 7) * 32, (bb & 127) * 32, tid, t);
    } else if (b < 10496) {
        int bb = b - 6400;                       // W2: K=4096, N=1024
        transpose_body(W2, W2t, HID1, HID2, (bb >> 5) * 32, (bb & 31) * 32, tid, t);
    } else {
        // W3 [1024,10] f32 -> w3b [10][W3B_STRIDE] bf16 (transposed)
        for (int i = tid; i < HID2 * F_OUT; i += 256) {
            int k = i / F_OUT, c = i % F_OUT;
            w3b[c * W3B_STRIDE + k] = f2bf(W3[i]);
        }
    }
}

// ---------------------------------------------------------------------------
// agg1: agg_x[v,:] = sum_e w_e*xb[src,:] + xb[v,:]/(deg+1) -> bf16
// ---------------------------------------------------------------------------
__global__ __launch_bounds__(256) void agg1_kernel(
        const unsigned short* __restrict__ xb, const int* __restrict__ row_ptr,
        const int* __restrict__ csr_src, const float* __restrict__ csr_w,
        const int* __restrict__ deg, unsigned short* __restrict__ out) {
    int v = blockIdx.x * 4 + (threadIdx.x >> 6);
    int t = threadIdx.x & 63;
    const uint4* xp = (const uint4*)xb;        // row stride 64 uint4
    float sw = 1.0f / (float)(deg[v] + 1);
    float acc[8], tmp[8];
    unpack8(xp[(size_t)v * 64 + t], tmp);
#pragma unroll
    for (int j = 0; j < 8; j++) acc[j] = sw * tmp[j];
    int e = row_ptr[v], end = row_ptr[v + 1];
    for (; e + 4 <= end; e += 4) {
        int s0 = csr_src[e], s1 = csr_src[e + 1];
        int s2 = csr_src[e + 2], s3 = csr_src[e + 3];
        float w0 = csr_w[e], w1 = csr_w[e + 1];
        float w2 = csr_w[e + 2], w3 = csr_w[e + 3];
        float f0[8], f1[8], f2[8], f3[8];
        unpack8(xp[(size_t)s0 * 64 + t], f0);
        unpack8(xp[(size_t)s1 * 64 + t], f1);
        unpack8(xp[(size_t)s2 * 64 + t], f2);
        unpack8(xp[(size_t)s3 * 64 + t], f3);
#pragma unroll
        for (int j = 0; j < 8; j++)
            acc[j] += w0 * f0[j] + w1 * f1[j] + w2 * f2[j] + w3 * f3[j];
    }
    for (; e < end; e++) {
        int s = csr_src[e];
        float w = csr_w[e];
        float f0[8];
        unpack8(xp[(size_t)s * 64 + t], f0);
#pragma unroll
        for (int j = 0; j < 8; j++) acc[j] += w * f0[j];
    }
    ((uint4*)out)[(size_t)v * 64 + t] = pack8(acc);
}

// ---------------------------------------------------------------------------
// agg2 + gemm3 fused.
// ---------------------------------------------------------------------------
__global__ __launch_bounds__(256) void agg2_gemm3_kernel(
        const unsigned short* __restrict__ h, const int* __restrict__ row_ptr,
        const int* __restrict__ csr_src, const float* __restrict__ csr_w,
        const int* __restrict__ deg, const float* __restrict__ b2,
        const unsigned short* __restrict__ w3b, float* __restrict__ H3) {
    __shared__ unsigned short w3s[F_OUT * W3B_STRIDE];   // ~20.2 KB
    __shared__ float red[4][F_OUT];
    int tid = threadIdx.x;
    for (int i = tid; i < F_OUT * W3B_STRIDE; i += 256) w3s[i] = w3b[i];
    __syncthreads();
    int half = tid >> 7;
    int t = tid & 127;
    int v = blockIdx.x * 2 + half;
    const uint4* hp = (const uint4*)h;   // row stride 128 uint4
    float sw = 1.0f / (float)(deg[v] + 1);
    float acc[8], tmp[8];
    unpack8(hp[(size_t)v * 128 + t], tmp);
#pragma unroll
    for (int j = 0; j < 8; j++) acc[j] = sw * tmp[j];
    int e = row_ptr[v], end = row_ptr[v + 1];
    for (; e + 4 <= end; e += 4) {
        int s0 = csr_src[e], s1 = csr_src[e + 1];
        int s2 = csr_src[e + 2], s3 = csr_src[e + 3];
        float w0 = csr_w[e], w1 = csr_w[e + 1];
        float w2 = csr_w[e + 2], w3 = csr_w[e + 3];
        float f0[8], f1[8], f2[8], f3[8];
        unpack8(hp[(size_t)s0 * 128 + t], f0);
        unpack8(hp[(size_t)s1 * 128 + t], f1);
        unpack8(hp[(size_t)s2 * 128 + t], f2);
        unpack8(hp[(size_t)s3 * 128 + t], f3);
#pragma unroll
        for (int j = 0; j < 8; j++)
            acc[j] += w0 * f0[j] + w1 * f1[j] + w2 * f2[j] + w3 * f3[j];
    }
    for (; e < end; e++) {
        int s = csr_src[e];
        float w = csr_w[e];
        float f0[8];
        unpack8(hp[(size_t)s * 128 + t], f0);
#pragma unroll
        for (int j = 0; j < 8; j++) acc[j] += w * f0[j];
    }
    float4 b4a = ((const float4*)b2)[t * 2];
    float4 b4b = ((const float4*)b2)[t * 2 + 1];
    acc[0] = fmaxf(acc[0] + b4a.x, 0.0f); acc[1] = fmaxf(acc[1] + b4a.y, 0.0f);
    acc[2] = fmaxf(acc[2] + b4a.z, 0.0f); acc[3] = fmaxf(acc[3] + b4a.w, 0.0f);
    acc[4] = fmaxf(acc[4] + b4b.x, 0.0f); acc[5] = fmaxf(acc[5] + b4b.y, 0.0f);
    acc[6] = fmaxf(acc[6] + b4b.z, 0.0f); acc[7] = fmaxf(acc[7] + b4b.w, 0.0f);

    float partial[F_OUT];
#pragma unroll
    for (int c = 0; c < F_OUT; c++) {
        float wf[8];
        unpack8(*(const uint4*)&w3s[c * W3B_STRIDE + t * 8], wf);
        partial[c] = acc[0] * wf[0] + acc[1] * wf[1] + acc[2] * wf[2] + acc[3] * wf[3]
                   + acc[4] * wf[4] + acc[5] * wf[5] + acc[6] * wf[6] + acc[7] * wf[7];
    }
#pragma unroll
    for (int c = 0; c < F_OUT; c++) {
#pragma unroll
        for (int off = 32; off > 0; off >>= 1)
            partial[c] += __shfl_xor(partial[c], off, 64);
    }
    int wave = tid >> 6, lane = tid & 63;
    if (lane == 0) {
#pragma unroll
        for (int c = 0; c < F_OUT; c++) red[wave][c] = partial[c];
    }
    __syncthreads();
    if (tid < 2 * F_OUT) {
        int hh = tid / F_OUT, c = tid % F_OUT;
        H3[(size_t)(blockIdx.x * 2 + hh) * H3_STRIDE + c] =
            red[hh * 2][c] + red[hh * 2 + 1][c];
    }
}

// ---------------------------------------------------------------------------
// GEMM1 (R4): true 8-phase schedule (m201 port). BM=BN=256, BK=64, 8 waves
// (2M x 4N), wave-tile 128x64 (acc[4][2] of 32x32x16). LDS 128 KB =
// 2 dbuf x 2 K-halves x (A 16KB + B 16KB). Per K-tile: 4 phases (one per
// k16-step): {6 ds_reads, stage one half-tile of t+1 (2 gloads), barrier,
// setprio(1), 8 MFMA, setprio(0), barrier}. Counted vmcnt(4) only at the
// two K-half boundaries -> 2 half-tiles (4 loads) stay in flight across
// every barrier; drains only at the final tile.
// LDS layout: 256B-stride 16-chunk XOR (the proven zero-conflict scheme):
// 4 rows per 256B super-row, chunk cs = ((R&3)*4+lc) ^ ((R>>2)&3).
// Staged with linear LDS dest + inverse-swizzled global source (rule #21).
// ---------------------------------------------------------------------------
#define P8_STAGE(mat_, kh_, dd_, base_, k0_) do {                              \
    unsigned short* L_ = lds + ((dd_) * 4 + (mat_) * 2 + (kh_)) * 8192;        \
    _Pragma("unroll")                                                          \
    for (int j = 0; j < 2; j++) {                                              \
        int slot = j * 512 + tid;                                              \
        int s4 = slot >> 4, cs = slot & 15;                                    \
        int csp = cs ^ (s4 & 3);                                               \
        int grow = s4 * 4 + (csp >> 2);                                        \
        int gcol = (csp & 3) * 8;                                              \
        __builtin_amdgcn_global_load_lds(                                      \
            (const __attribute__((address_space(1))) void*)((base_) + (size_t)grow * K + (k0_) + (kh_) * 32 + gcol), \
            (__attribute__((address_space(3))) void*)(&L_[slot * 8]), 16, 0, 0); \
    }                                                                          \
} while (0)

// element offset (ushort) of (row R, 16B-chunk lc in 0..3) within a khalf buf
#define P8_OFF(R_, lc_) ((((R_) >> 2) * 128) + (((((R_) & 3) << 2) | (lc_)) ^ (((R_) >> 2) & 3)) * 8)

__global__ __launch_bounds__(512, 2) void gemm1_pipe8_kernel(
        const unsigned short* __restrict__ A,   // [8192,512] bf16
        const unsigned short* __restrict__ Bt,  // [4096,512] bf16
        const float* __restrict__ bias,         // [4096]
        unsigned short* __restrict__ C) {       // [8192,4096] bf16
    __shared__ unsigned short lds[65536];       // 128 KB: [dbuf][mat][khalf][8192]
    const int K = F_IN, N = HID1;
    int tid = threadIdx.x;
    int wave = tid >> 6, lane = tid & 63;
    int wm = wave >> 2, wn = wave & 3;          // 2M x 4N, wave-tile 128x64
    int lrow = lane & 31, lhalf = lane >> 5;

    // Proven supertile mapping: 512 blocks = 16 ntiles x 32 mtiles.
    int b = blockIdx.x;
    int GN = HID1 >> 8;                         // 16
    int ntile = (b >> 3) % GN;
    int mtile = ((b >> 3) / GN) * 8 + (b & 7);  // 0..31
    int m0 = mtile * 256, n0 = ntile * 256;

    const unsigned short* Abase = A + (size_t)m0 * K;
    const unsigned short* Bbase = Bt + (size_t)n0 * K;

    floatx16 acc[4][2] = {};
    const int NT = K >> 6;                      // 8 K-tiles

    // Prologue: stage all 4 halves of tile 0 into dbuf 0; keep last 2 in flight.
    P8_STAGE(0, 0, 0, Abase, 0);
    P8_STAGE(1, 0, 0, Bbase, 0);
    P8_STAGE(0, 1, 0, Abase, 0);
    P8_STAGE(1, 1, 0, Bbase, 0);
    asm volatile("s_waitcnt vmcnt(4)" ::: "memory");
    __builtin_amdgcn_s_barrier();

    for (int t = 0; t < NT; t++) {
        int d = t & 1, dn = d ^ 1;
        int k1 = (t + 1) * 64;
#pragma unroll
        for (int kk = 0; kk < 4; kk++) {
            if (kk == 2) {                      // K-half boundary: kh1 must be landed
                if (t + 1 < NT)
                    asm volatile("s_waitcnt vmcnt(4)" ::: "memory");
                else
                    asm volatile("s_waitcnt vmcnt(0)" ::: "memory");
                __builtin_amdgcn_s_barrier();
            }
            int kh = kk >> 1;
            int lc0 = (kk & 1) * 2 + lhalf;     // 16B chunk 0..3 within khalf
            const unsigned short* Ak = lds + (d * 4 + kh) * 8192;
            const unsigned short* Bk = lds + (d * 4 + 2 + kh) * 8192;
            bf16x8 af[4], bfr[2];
#pragma unroll
            for (int mt = 0; mt < 4; mt++) {
                int R = wm * 128 + mt * 32 + lrow;
                af[mt] = *(const bf16x8*)&Ak[P8_OFF(R, lc0)];
            }
#pragma unroll
            for (int nt = 0; nt < 2; nt++) {
                int R = wn * 64 + nt * 32 + lrow;
                bfr[nt] = *(const bf16x8*)&Bk[P8_OFF(R, lc0)];
            }
            // stage one half of tile t+1 per phase: Ak0, Bk0, Ak1, Bk1
            if (t + 1 < NT) {
                if (kk == 0)      P8_STAGE(0, 0, dn, Abase, k1);
                else if (kk == 1) P8_STAGE(1, 0, dn, Bbase, k1);
                else if (kk == 2) P8_STAGE(0, 1, dn, Abase, k1);
                else              P8_STAGE(1, 1, dn, Bbase, k1);
            }
            __builtin_amdgcn_s_barrier();
            __builtin_amdgcn_s_setprio(1);
#pragma unroll
            for (int mt = 0; mt < 4; mt++)
#pragma unroll
                for (int nt = 0; nt < 2; nt++)
                    acc[mt][nt] = __builtin_amdgcn_mfma_f32_32x32x16_bf16(
                        af[mt], bfr[nt], acc[mt][nt], 0, 0, 0);
            __builtin_amdgcn_s_setprio(0);
            if (kk == 0 || kk == 2) __builtin_amdgcn_s_barrier();
            // kk==1: next phase's vmcnt+barrier is the boundary
            // kk==3: tile-end vmcnt+barrier below is the boundary
        }
        asm volatile("s_waitcnt vmcnt(4)" ::: "memory");  // next tile's kh0 landed
        __builtin_amdgcn_s_barrier();
    }

#pragma unroll
    for (int mt = 0; mt < 4; mt++) {
#pragma unroll
        for (int nt = 0; nt < 2; nt++) {
            int col = n0 + wn * 64 + nt * 32 + lrow;
            float bv = bias[col];
#pragma unroll
            for (int reg = 0; reg < 16; reg++) {
                int row = m0 + wm * 128 + mt * 32 + (reg & 3) + 8 * (reg >> 2) + 4 * lhalf;
                float v = fmaxf(acc[mt][nt][reg] + bv, 0.0f);
                C[(size_t)row * N + col] = f2bf(v);
            }
        }
    }
}

// ---------------------------------------------------------------------------
// GEMM2 (restored R0 verbatim): 128x128 tile, BK=128, 32x32x16 MFMA,
// global_load_lds staging, drained 2-barrier loop. 76.4 us, 0 conflicts.
// ---------------------------------------------------------------------------
template <bool OUT_BF16, bool BIAS, bool RELU>
__global__ __launch_bounds__(256) void gemm2_mfma_kernel(
        const unsigned short* __restrict__ A,   // [M,K] bf16
        const unsigned short* __restrict__ Bt,  // [N,K] bf16
        const float* __restrict__ bias,         // [N] or null
        void* __restrict__ C,                   // [M,N] bf16 or f32
        int M, int N, int K) {
    __shared__ unsigned short As[128 * 128];    // 32 KB
    __shared__ unsigned short Bs[128 * 128];    // 32 KB
    int tid = threadIdx.x;
    int wave = tid >> 6, lane = tid & 63;
    int wm = wave >> 1, wn = wave & 1;
    int GN = N >> 7;
    int b = blockIdx.x;
    int ntile = (b >> 3) % GN;
    int mtile = ((b >> 3) / GN) * 8 + (b & 7);
    int m0 = mtile * 128, n0 = ntile * 128;
    int lrow = lane & 31, lhalf = lane >> 5;

    floatx16 acc[2][2] = {};

    for (int k0 = 0; k0 < K; k0 += 128) {
#pragma unroll
        for (int j = 0; j < 8; j++) {           // 2048 16B slots per matrix
            int idx = j * 256 + tid;
            int r = idx >> 4;                   // row 0..127
            int kc = (idx & 15) ^ (r & 15);     // XOR swizzle on source chunk
            __builtin_amdgcn_global_load_lds(
                (const __attribute__((address_space(1))) void*)(A + (size_t)(m0 + r) * K + k0 + kc * 8),
                (__attribute__((address_space(3))) void*)(&As[idx * 8]), 16, 0, 0);
            __builtin_amdgcn_global_load_lds(
                (const __attribute__((address_space(1))) void*)(Bt + (size_t)(n0 + r) * K + k0 + kc * 8),
                (__attribute__((address_space(3))) void*)(&Bs[idx * 8]), 16, 0, 0);
        }
        __syncthreads();
#pragma unroll
        for (int kk = 0; kk < 8; kk++) {        // k-16 steps
            bf16x8 af[2], bfr[2];
            int c = kk * 2 + lhalf;             // source chunk 0..15
#pragma unroll
            for (int mt = 0; mt < 2; mt++) {
                int R = wm * 64 + mt * 32 + lrow;
                af[mt] = *(const bf16x8*)&As[(R * 16 + (c ^ (R & 15))) * 8];
            }
#pragma unroll
            for (int nt = 0; nt < 2; nt++) {
                int R = wn * 64 + nt * 32 + lrow;
                bfr[nt] = *(const bf16x8*)&Bs[(R * 16 + (c ^ (R & 15))) * 8];
            }
#pragma unroll
            for (int mt = 0; mt < 2; mt++)
#pragma unroll
                for (int nt = 0; nt < 2; nt++)
                    acc[mt][nt] = __builtin_amdgcn_mfma_f32_32x32x16_bf16(
                        af[mt], bfr[nt], acc[mt][nt], 0, 0, 0);
        }
        __syncthreads();
    }

#pragma unroll
    for (int mt = 0; mt < 2; mt++) {
#pragma unroll
        for (int nt = 0; nt < 2; nt++) {
            int col = n0 + wn * 64 + nt * 32 + lrow;
            float bv = BIAS ? bias[col] : 0.0f;
#pragma unroll
            for (int reg = 0; reg < 16; reg++) {
                int row = m0 + wm * 64 + mt * 32 + (reg & 3) + 8 * (reg >> 2) + 4 * lhalf;
                float v = acc[mt][nt][reg] + bv;
                if (RELU) v = fmaxf(v, 0.0f);
                if (OUT_BF16)
                    ((unsigned short*)C)[(size_t)row * N + col] = f2bf(v);
                else
                    ((float*)C)[(size_t)row * N + col] = v;
            }
        }
    }
}

// ---------------------------------------------------------------------------
// Final: aggregate h3 (stride 16), add b3, log_softmax per node.
// ---------------------------------------------------------------------------
__global__ void final_kernel(const float* __restrict__ h3, const int* __restrict__ row_ptr,
                             const int* __restrict__ csr_src, const float* __restrict__ csr_w,
                             const int* __restrict__ deg, const float* __restrict__ b3,
                             float* __restrict__ out) {
    int v = blockIdx.x * blockDim.x + threadIdx.x;
    if (v >= N_NODES) return;
    const float4* h4 = (const float4*)h3;
    float sw = 1.0f / (float)(deg[v] + 1);
    float a[12];
    *(float4*)&a[0] = h4[v * 4];
    *(float4*)&a[4] = h4[v * 4 + 1];
    *(float4*)&a[8] = h4[v * 4 + 2];
    float acc[F_OUT];
#pragma unroll
    for (int c = 0; c < F_OUT; c++) acc[c] = b3[c] + sw * a[c];
    int end = row_ptr[v + 1];
    for (int e = row_ptr[v]; e < end; e++) {
        int s = csr_src[e];
        float w = csr_w[e];
        float bsrc[12];
        *(float4*)&bsrc[0] = h4[s * 4];
        *(float4*)&bsrc[4] = h4[s * 4 + 1];
        *(float4*)&bsrc[8] = h4[s * 4 + 2];
#pragma unroll
        for (int c = 0; c < F_OUT; c++) acc[c] += w * bsrc[c];
    }
    float m = acc[0];
#pragma unroll
    for (int c = 1; c < F_OUT; c++) m = fmaxf(m, acc[c]);
    float ssum = 0.0f;
#pragma unroll
    for (int c = 0; c < F_OUT; c++) ssum += expf(acc[c] - m);
    float l = logf(ssum);
#pragma unroll
    for (int c = 0; c < F_OUT; c++) out[v * F_OUT + c] = acc[c] - m - l;
}

// ---------------------------------------------------------------------------
// Launch (7 dispatches)
// ---------------------------------------------------------------------------
extern "C" void kernel_launch(void* const* d_in, const int* in_sizes, int n_in,
                              void* d_out, int out_size, void* d_ws, size_t ws_size,
                              hipStream_t stream) {
    const float* x  = (const float*)d_in[0];
    const float* W1 = (const float*)d_in[1];
    const float* b1 = (const float*)d_in[2];
    const float* W2 = (const float*)d_in[3];
    const float* b2 = (const float*)d_in[4];
    const float* W3 = (const float*)d_in[5];
    const float* b3 = (const float*)d_in[6];
    const int*   ei = (const int*)d_in[7];
    float* out = (float*)d_out;

    char* p = (char*)d_ws;
    int*   deg     = (int*)p;    p += N_NODES * 4;
    int*   cnt     = (int*)p;    p += N_NODES * 4;
    int*   row_ptr = (int*)p;    p += 33024;
    int*   csr_src = (int*)p;    p += N_EDGES * 4;
    float* csr_w   = (float*)p;  p += N_EDGES * 4;
    float* h3      = (float*)p;  p += N_NODES * H3_STRIDE * 4;
    unsigned short* w3b = (unsigned short*)p; p += (F_OUT * W3B_STRIDE * 2 + 255) / 256 * 256;
    unsigned short* xb    = (unsigned short*)p; p += (size_t)N_NODES * F_IN * 2;
    unsigned short* agg_x = (unsigned short*)p; p += (size_t)N_NODES * F_IN * 2;
    unsigned short* W1t   = (unsigned short*)p; p += (size_t)HID1 * F_IN * 2;
    unsigned short* W2t   = (unsigned short*)p; p += (size_t)HID2 * HID1 * 2;
    unsigned short* h1    = (unsigned short*)p; p += (size_t)N_NODES * HID1 * 2;
    unsigned short* h2pre = (unsigned short*)p; p += (size_t)N_NODES * HID2 * 2;

    // Graph preprocessing + all conversions (2 launches)
    hist_scan_kernel<<<1, 1024, 0, stream>>>(ei, deg, row_ptr, cnt);
    megaprep_kernel<<<10497, 256, 0, stream>>>(ei, deg, row_ptr, cnt, csr_src, csr_w,
                                               x, xb, W1, W1t, W2, W2t, W3, w3b);

    // Layer 1: 8-phase pipelined 256^2 GEMM (512 blocks x 512 threads)
    agg1_kernel<<<N_NODES / 4, 256, 0, stream>>>(xb, row_ptr, csr_src, csr_w, deg, agg_x);
    gemm1_pipe8_kernel<<<(N_NODES / 256) * (HID1 / 256) * 8 / 8, 512, 0, stream>>>(
        agg_x, W1t, b1, h1);

    // Layer 2: proven 128^2 BK=128 drained kernel (76.4 us, 0 conflicts)
    gemm2_mfma_kernel<true, false, false><<<(HID2 / 128) * (N_NODES / 128), 256, 0, stream>>>(
        h1, W2t, nullptr, h2pre, N_NODES, HID2, HID1);

    // Layer 2 aggregation + Layer 3 GEMM fused
    agg2_gemm3_kernel<<<N_NODES / 2, 256, 0, stream>>>(h2pre, row_ptr, csr_src, csr_w,
                                                       deg, b2, w3b, h3);

    // Output
    final_kernel<<<N_NODES / 256, 256, 0, stream>>>(h3, row_ptr, csr_src, csr_w, deg, b3, out);
}

// Round 5
// 274.641 us; speedup vs baseline: 1.0839x; 1.0342x over previous
//
#include <hip/hip_runtime.h>
#include <math.h>

#define N_NODES 8192
#define N_EDGES 65536
#define F_IN    512
#define HID1    4096
#define HID2    1024
#define F_OUT   10
#define H3_STRIDE 16
#define W3B_STRIDE 1032   // padded K-stride of bf16 W3^T rows

typedef __bf16 bf16x8 __attribute__((ext_vector_type(8)));
typedef float floatx4 __attribute__((ext_vector_type(4)));
typedef float floatx16 __attribute__((ext_vector_type(16)));

static __device__ __forceinline__ unsigned short f2bf(float f) {
    union { float f; unsigned u; } v; v.f = f;
    unsigned r = v.u + 0x7fffu + ((v.u >> 16) & 1u);   // RNE
    return (unsigned short)(r >> 16);
}
static __device__ __forceinline__ float bf2f(unsigned short u) {
    union { unsigned u; float f; } v; v.u = ((unsigned)u) << 16;
    return v.f;
}
static __device__ __forceinline__ void unpack8(uint4 r, float* f) {
    union { unsigned u; float v; } c;
    c.u = r.x << 16;          f[0] = c.v;
    c.u = r.x & 0xffff0000u;  f[1] = c.v;
    c.u = r.y << 16;          f[2] = c.v;
    c.u = r.y & 0xffff0000u;  f[3] = c.v;
    c.u = r.z << 16;          f[4] = c.v;
    c.u = r.z & 0xffff0000u;  f[5] = c.v;
    c.u = r.w << 16;          f[6] = c.v;
    c.u = r.w & 0xffff0000u;  f[7] = c.v;
}
static __device__ __forceinline__ uint4 pack8(const float* f) {
    uint4 o;
    o.x = (unsigned)f2bf(f[0]) | ((unsigned)f2bf(f[1]) << 16);
    o.y = (unsigned)f2bf(f[2]) | ((unsigned)f2bf(f[3]) << 16);
    o.z = (unsigned)f2bf(f[4]) | ((unsigned)f2bf(f[5]) << 16);
    o.w = (unsigned)f2bf(f[6]) | ((unsigned)f2bf(f[7]) << 16);
    return o;
}

// ---------------------------------------------------------------------------
// hist+scan (one block): deg[] via LDS histogram (int4-vectorized loads),
// exclusive scan -> row_ptr, cnt[] zeroing.
// ---------------------------------------------------------------------------
__global__ __launch_bounds__(1024) void hist_scan_kernel(
        const int* __restrict__ ei, int* __restrict__ deg,
        int* __restrict__ row_ptr, int* __restrict__ cnt) {
    __shared__ int hist[N_NODES];        // 32 KB
    __shared__ int sums[1024];
    int t = threadIdx.x;
#pragma unroll
    for (int i = 0; i < 8; i++) hist[t + i * 1024] = 0;
    __syncthreads();
    const int4* ei4 = (const int4*)(ei + N_EDGES);
#pragma unroll
    for (int i = 0; i < 16; i++) {
        int4 d4 = ei4[i * 1024 + t];
        atomicAdd(&hist[d4.x], 1);
        atomicAdd(&hist[d4.y], 1);
        atomicAdd(&hist[d4.z], 1);
        atomicAdd(&hist[d4.w], 1);
    }
    __syncthreads();
    int base = t * 8;
    int local[8], run = 0;
#pragma unroll
    for (int i = 0; i < 8; i++) {
        int dv = hist[base + i];
        deg[base + i] = dv;
        cnt[base + i] = 0;
        local[i] = run; run += dv;
    }
    sums[t] = run;
    __syncthreads();
    for (int off = 1; off < 1024; off <<= 1) {
        int val = (t >= off) ? sums[t - off] : 0;
        __syncthreads();
        sums[t] += val;
        __syncthreads();
    }
    int offset = (t == 0) ? 0 : sums[t - 1];
#pragma unroll
    for (int i = 0; i < 8; i++) row_ptr[base + i] = offset + local[i];
    if (t == 1023) row_ptr[N_NODES] = sums[1023];
}

// ---------------------------------------------------------------------------
// megaprep: fill CSR (blocks 0..255) + xcvt (256..4351) + W1^T (4352..6399)
// + W2^T (6400..10495) + W3 bf16 cvt (10496). One launch.
// ---------------------------------------------------------------------------
static __device__ __forceinline__ void transpose_body(
        const float* __restrict__ W, unsigned short* __restrict__ Wt,
        int K, int N, int k0, int n0, int tid, float (*t)[33]) {
    int c = tid & 31, r8 = tid >> 5;
#pragma unroll
    for (int i = 0; i < 4; i++) {
        int r = r8 + i * 8;
        t[r][c] = W[(size_t)(k0 + r) * N + n0 + c];
    }
    __syncthreads();
#pragma unroll
    for (int i = 0; i < 4; i++) {
        int r = r8 + i * 8;
        Wt[(size_t)(n0 + r) * K + k0 + c] = f2bf(t[c][r]);
    }
}

__global__ __launch_bounds__(256) void megaprep_kernel(
        const int* __restrict__ ei, const int* __restrict__ deg,
        const int* __restrict__ row_ptr, int* __restrict__ cnt,
        int* __restrict__ csr_src, float* __restrict__ csr_w,
        const float* __restrict__ x, unsigned short* __restrict__ xb,
        const float* __restrict__ W1, unsigned short* __restrict__ W1t,
        const float* __restrict__ W2, unsigned short* __restrict__ W2t,
        const float* __restrict__ W3, unsigned short* __restrict__ w3b) {
    __shared__ float t[32][33];
    int b = blockIdx.x, tid = threadIdx.x;
    if (b < 256) {
        int e = b * 256 + tid;
        int s = ei[e];
        int d = ei[N_EDGES + e];
        int slot = row_ptr[d] + atomicAdd(&cnt[d], 1);
        csr_src[slot] = s;
        csr_w[slot] = rsqrtf((float)((deg[s] + 1) * (deg[d] + 1)));
    } else if (b < 4352) {
        int i = (b - 256) * 256 + tid;
        float4 a = ((const float4*)x)[i];
        ushort4 o;
        o.x = f2bf(a.x); o.y = f2bf(a.y); o.z = f2bf(a.z); o.w = f2bf(a.w);
        ((ushort4*)xb)[i] = o;
    } else if (b < 6400) {
        int bb = b - 4352;                       // W1: K=512, N=4096
        transpose_body(W1, W1t, F_IN, HID1, (bb >> 7) * 32, (bb & 127) * 32, tid, t);
    } else if (b < 10496) {
        int bb = b - 6400;                       // W2: K=4096, N=1024
        transpose_body(W2, W2t, HID1, HID2, (bb >> 5) * 32, (bb & 31) * 32, tid, t);
    } else {
        // W3 [1024,10] f32 -> w3b [10][W3B_STRIDE] bf16 (transposed)
        for (int i = tid; i < HID2 * F_OUT; i += 256) {
            int k = i / F_OUT, c = i % F_OUT;
            w3b[c * W3B_STRIDE + k] = f2bf(W3[i]);
        }
    }
}

// ---------------------------------------------------------------------------
// agg1: agg_x[v,:] = sum_e w_e*xb[src,:] + xb[v,:]/(deg+1) -> bf16
// ---------------------------------------------------------------------------
__global__ __launch_bounds__(256) void agg1_kernel(
        const unsigned short* __restrict__ xb, const int* __restrict__ row_ptr,
        const int* __restrict__ csr_src, const float* __restrict__ csr_w,
        const int* __restrict__ deg, unsigned short* __restrict__ out) {
    int v = blockIdx.x * 4 + (threadIdx.x >> 6);
    int t = threadIdx.x & 63;
    const uint4* xp = (const uint4*)xb;        // row stride 64 uint4
    float sw = 1.0f / (float)(deg[v] + 1);
    float acc[8], tmp[8];
    unpack8(xp[(size_t)v * 64 + t], tmp);
#pragma unroll
    for (int j = 0; j < 8; j++) acc[j] = sw * tmp[j];
    int e = row_ptr[v], end = row_ptr[v + 1];
    for (; e + 4 <= end; e += 4) {
        int s0 = csr_src[e], s1 = csr_src[e + 1];
        int s2 = csr_src[e + 2], s3 = csr_src[e + 3];
        float w0 = csr_w[e], w1 = csr_w[e + 1];
        float w2 = csr_w[e + 2], w3 = csr_w[e + 3];
        float f0[8], f1[8], f2[8], f3[8];
        unpack8(xp[(size_t)s0 * 64 + t], f0);
        unpack8(xp[(size_t)s1 * 64 + t], f1);
        unpack8(xp[(size_t)s2 * 64 + t], f2);
        unpack8(xp[(size_t)s3 * 64 + t], f3);
#pragma unroll
        for (int j = 0; j < 8; j++)
            acc[j] += w0 * f0[j] + w1 * f1[j] + w2 * f2[j] + w3 * f3[j];
    }
    for (; e < end; e++) {
        int s = csr_src[e];
        float w = csr_w[e];
        float f0[8];
        unpack8(xp[(size_t)s * 64 + t], f0);
#pragma unroll
        for (int j = 0; j < 8; j++) acc[j] += w * f0[j];
    }
    ((uint4*)out)[(size_t)v * 64 + t] = pack8(acc);
}

// ---------------------------------------------------------------------------
// agg2 + gemm3 fused.
// ---------------------------------------------------------------------------
__global__ __launch_bounds__(256) void agg2_gemm3_kernel(
        const unsigned short* __restrict__ h, const int* __restrict__ row_ptr,
        const int* __restrict__ csr_src, const float* __restrict__ csr_w,
        const int* __restrict__ deg, const float* __restrict__ b2,
        const unsigned short* __restrict__ w3b, float* __restrict__ H3) {
    __shared__ unsigned short w3s[F_OUT * W3B_STRIDE];   // ~20.2 KB
    __shared__ float red[4][F_OUT];
    int tid = threadIdx.x;
    for (int i = tid; i < F_OUT * W3B_STRIDE; i += 256) w3s[i] = w3b[i];
    __syncthreads();
    int half = tid >> 7;
    int t = tid & 127;
    int v = blockIdx.x * 2 + half;
    const uint4* hp = (const uint4*)h;   // row stride 128 uint4
    float sw = 1.0f / (float)(deg[v] + 1);
    float acc[8], tmp[8];
    unpack8(hp[(size_t)v * 128 + t], tmp);
#pragma unroll
    for (int j = 0; j < 8; j++) acc[j] = sw * tmp[j];
    int e = row_ptr[v], end = row_ptr[v + 1];
    for (; e + 4 <= end; e += 4) {
        int s0 = csr_src[e], s1 = csr_src[e + 1];
        int s2 = csr_src[e + 2], s3 = csr_src[e + 3];
        float w0 = csr_w[e], w1 = csr_w[e + 1];
        float w2 = csr_w[e + 2], w3 = csr_w[e + 3];
        float f0[8], f1[8], f2[8], f3[8];
        unpack8(hp[(size_t)s0 * 128 + t], f0);
        unpack8(hp[(size_t)s1 * 128 + t], f1);
        unpack8(hp[(size_t)s2 * 128 + t], f2);
        unpack8(hp[(size_t)s3 * 128 + t], f3);
#pragma unroll
        for (int j = 0; j < 8; j++)
            acc[j] += w0 * f0[j] + w1 * f1[j] + w2 * f2[j] + w3 * f3[j];
    }
    for (; e < end; e++) {
        int s = csr_src[e];
        float w = csr_w[e];
        float f0[8];
        unpack8(hp[(size_t)s * 128 + t], f0);
#pragma unroll
        for (int j = 0; j < 8; j++) acc[j] += w * f0[j];
    }
    float4 b4a = ((const float4*)b2)[t * 2];
    float4 b4b = ((const float4*)b2)[t * 2 + 1];
    acc[0] = fmaxf(acc[0] + b4a.x, 0.0f); acc[1] = fmaxf(acc[1] + b4a.y, 0.0f);
    acc[2] = fmaxf(acc[2] + b4a.z, 0.0f); acc[3] = fmaxf(acc[3] + b4a.w, 0.0f);
    acc[4] = fmaxf(acc[4] + b4b.x, 0.0f); acc[5] = fmaxf(acc[5] + b4b.y, 0.0f);
    acc[6] = fmaxf(acc[6] + b4b.z, 0.0f); acc[7] = fmaxf(acc[7] + b4b.w, 0.0f);

    float partial[F_OUT];
#pragma unroll
    for (int c = 0; c < F_OUT; c++) {
        float wf[8];
        unpack8(*(const uint4*)&w3s[c * W3B_STRIDE + t * 8], wf);
        partial[c] = acc[0] * wf[0] + acc[1] * wf[1] + acc[2] * wf[2] + acc[3] * wf[3]
                   + acc[4] * wf[4] + acc[5] * wf[5] + acc[6] * wf[6] + acc[7] * wf[7];
    }
#pragma unroll
    for (int c = 0; c < F_OUT; c++) {
#pragma unroll
        for (int off = 32; off > 0; off >>= 1)
            partial[c] += __shfl_xor(partial[c], off, 64);
    }
    int wave = tid >> 6, lane = tid & 63;
    if (lane == 0) {
#pragma unroll
        for (int c = 0; c < F_OUT; c++) red[wave][c] = partial[c];
    }
    __syncthreads();
    if (tid < 2 * F_OUT) {
        int hh = tid / F_OUT, c = tid % F_OUT;
        H3[(size_t)(blockIdx.x * 2 + hh) * H3_STRIDE + c] =
            red[hh * 2][c] + red[hh * 2 + 1][c];
    }
}

// ---------------------------------------------------------------------------
// 8-phase pipelined GEMM body (m201 port, refcheck-verified in R4).
// 8 waves (2M x 4N), wave-tile 128x64, BK=64 in 2 K-halves, LDS 128 KB =
// 2 dbuf x 2 khalf x (A 16KB + B 16KB). Counted vmcnt(4) at half-tile
// boundaries; drains only at the last tile. 256B-stride 16-chunk XOR LDS
// layout (analytically uniform banks for b128 reads); linear LDS dest +
// inverse-swizzled global source (rule #21).
// ---------------------------------------------------------------------------
#define P8_STAGE(mat_, kh_, dd_, base_, k0_) do {                              \
    unsigned short* L_ = lds + ((dd_) * 4 + (mat_) * 2 + (kh_)) * 8192;        \
    _Pragma("unroll")                                                          \
    for (int j = 0; j < 2; j++) {                                              \
        int slot = j * 512 + tid;                                              \
        int s4 = slot >> 4, cs = slot & 15;                                    \
        int csp = cs ^ (s4 & 3);                                               \
        int grow = s4 * 4 + (csp >> 2);                                        \
        int gcol = (csp & 3) * 8;                                              \
        __builtin_amdgcn_global_load_lds(                                      \
            (const __attribute__((address_space(1))) void*)((base_) + (size_t)grow * K + (k0_) + (kh_) * 32 + gcol), \
            (__attribute__((address_space(3))) void*)(&L_[slot * 8]), 16, 0, 0); \
    }                                                                          \
} while (0)

// element offset (ushort) of (row R, 16B-chunk lc in 0..3) within a khalf buf
#define P8_OFF(R_, lc_) ((((R_) >> 2) * 128) + (((((R_) & 3) << 2) | (lc_)) ^ (((R_) >> 2) & 3)) * 8)

#define P8_MAIN_LOOP(NT_)                                                      \
    P8_STAGE(0, 0, 0, Abase, 0);                                               \
    P8_STAGE(1, 0, 0, Bbase, 0);                                               \
    P8_STAGE(0, 1, 0, Abase, 0);                                               \
    P8_STAGE(1, 1, 0, Bbase, 0);                                               \
    asm volatile("s_waitcnt vmcnt(4)" ::: "memory");                           \
    __builtin_amdgcn_s_barrier();                                              \
    for (int t = 0; t < (NT_); t++) {                                          \
        int d = t & 1, dn = d ^ 1;                                             \
        int k1 = (t + 1) * 64;                                                 \
        _Pragma("unroll")                                                      \
        for (int kk = 0; kk < 4; kk++) {                                       \
            if (kk == 2) {                                                     \
                if (t + 1 < (NT_))                                             \
                    asm volatile("s_waitcnt vmcnt(4)" ::: "memory");           \
                else                                                           \
                    asm volatile("s_waitcnt vmcnt(0)" ::: "memory");           \
                __builtin_amdgcn_s_barrier();                                  \
            }                                                                  \
            int kh = kk >> 1;                                                  \
            int lc0 = (kk & 1) * 2 + lhalf;                                    \
            const unsigned short* Ak = lds + (d * 4 + kh) * 8192;              \
            const unsigned short* Bk = lds + (d * 4 + 2 + kh) * 8192;          \
            bf16x8 af[4], bfr[2];                                              \
            _Pragma("unroll")                                                  \
            for (int mt = 0; mt < 4; mt++) {                                   \
                int R = wm * 128 + mt * 32 + lrow;                             \
                af[mt] = *(const bf16x8*)&Ak[P8_OFF(R, lc0)];                  \
            }                                                                  \
            _Pragma("unroll")                                                  \
            for (int nt = 0; nt < 2; nt++) {                                   \
                int R = wn * 64 + nt * 32 + lrow;                              \
                bfr[nt] = *(const bf16x8*)&Bk[P8_OFF(R, lc0)];                 \
            }                                                                  \
            if (t + 1 < (NT_)) {                                               \
                if (kk == 0)      P8_STAGE(0, 0, dn, Abase, k1);               \
                else if (kk == 1) P8_STAGE(1, 0, dn, Bbase, k1);               \
                else if (kk == 2) P8_STAGE(0, 1, dn, Abase, k1);               \
                else              P8_STAGE(1, 1, dn, Bbase, k1);               \
            }                                                                  \
            __builtin_amdgcn_s_barrier();                                      \
            __builtin_amdgcn_s_setprio(1);                                     \
            _Pragma("unroll")                                                  \
            for (int mt = 0; mt < 4; mt++)                                     \
                _Pragma("unroll")                                              \
                for (int nt = 0; nt < 2; nt++)                                 \
                    acc[mt][nt] = __builtin_amdgcn_mfma_f32_32x32x16_bf16(     \
                        af[mt], bfr[nt], acc[mt][nt], 0, 0, 0);                \
            __builtin_amdgcn_s_setprio(0);                                     \
            if (kk == 0 || kk == 2) __builtin_amdgcn_s_barrier();              \
        }                                                                      \
        asm volatile("s_waitcnt vmcnt(4)" ::: "memory");                       \
        __builtin_amdgcn_s_barrier();                                          \
    }

// ---------------------------------------------------------------------------
// GEMM1: agg_x[8192,512] @ W1t -> relu(+b1) -> h1 bf16 [8192,4096].
// 512 blocks (16 ntiles x 32 mtiles), 512 threads, 8-phase schedule.
// ---------------------------------------------------------------------------
__global__ __launch_bounds__(512, 2) void gemm1_pipe8_kernel(
        const unsigned short* __restrict__ A,   // [8192,512] bf16
        const unsigned short* __restrict__ Bt,  // [4096,512] bf16
        const float* __restrict__ bias,         // [4096]
        unsigned short* __restrict__ C) {       // [8192,4096] bf16
    __shared__ unsigned short lds[65536];       // 128 KB
    const int K = F_IN, N = HID1;
    int tid = threadIdx.x;
    int wave = tid >> 6, lane = tid & 63;
    int wm = wave >> 2, wn = wave & 3;          // 2M x 4N, wave-tile 128x64
    int lrow = lane & 31, lhalf = lane >> 5;

    int b = blockIdx.x;
    int GN = HID1 >> 8;                         // 16
    int ntile = (b >> 3) % GN;
    int mtile = ((b >> 3) / GN) * 8 + (b & 7);  // 0..31
    int m0 = mtile * 256, n0 = ntile * 256;

    const unsigned short* Abase = A + (size_t)m0 * K;
    const unsigned short* Bbase = Bt + (size_t)n0 * K;

    floatx16 acc[4][2] = {};
    P8_MAIN_LOOP(8)                             // K=512 -> 8 K-tiles

#pragma unroll
    for (int mt = 0; mt < 4; mt++) {
#pragma unroll
        for (int nt = 0; nt < 2; nt++) {
            int col = n0 + wn * 64 + nt * 32 + lrow;
            float bv = bias[col];
#pragma unroll
            for (int reg = 0; reg < 16; reg++) {
                int row = m0 + wm * 128 + mt * 32 + (reg & 3) + 8 * (reg >> 2) + 4 * lhalf;
                float v = fmaxf(acc[mt][nt][reg] + bv, 0.0f);
                C[(size_t)row * N + col] = f2bf(v);
            }
        }
    }
}

// ---------------------------------------------------------------------------
// GEMM2 split-K (R5): h1[8192,4096] @ W2t -> bf16 partials. Grid 256 =
// 32 mtiles x 4 ntiles x 2 k-splits, each block = full-chip 8-phase 256^2
// schedule over K=2048. ksp=0 -> Ca (dead xb/agg_x region), ksp=1 -> Cb
// (h2pre region, merged in-place afterwards).
// ---------------------------------------------------------------------------
__global__ __launch_bounds__(512, 2) void gemm2_pipe8_split_kernel(
        const unsigned short* __restrict__ A,   // [8192,4096] bf16 (h1)
        const unsigned short* __restrict__ Bt,  // [1024,4096] bf16 (W2t)
        unsigned short* __restrict__ Ca,        // [8192,1024] bf16 partial k0
        unsigned short* __restrict__ Cb) {      // [8192,1024] bf16 partial k1
    __shared__ unsigned short lds[65536];       // 128 KB
    const int K = HID1;                         // row stride of A and Bt
    const int N = HID2;
    int tid = threadIdx.x;
    int wave = tid >> 6, lane = tid & 63;
    int wm = wave >> 2, wn = wave & 3;          // 2M x 4N, wave-tile 128x64
    int lrow = lane & 31, lhalf = lane >> 5;

    // Supertile mapping over (mtile 0..31, ntile 0..3, ksp 0..1):
    // b&7 -> mtile low (XCD slot shares A panel), u=b>>3: col=u&7 ->
    // (ntile,ksp), mrow=u>>3 -> mtile high.
    int b = blockIdx.x;
    int u = b >> 3;
    int col = u & 7;
    int mtile = (u >> 3) * 8 + (b & 7);         // 0..31
    int ntile = col >> 1;                       // 0..3
    int ksp = col & 1;
    int m0 = mtile * 256, n0 = ntile * 256;
    int koff = ksp * (HID1 / 2);

    const unsigned short* Abase = A + (size_t)m0 * K + koff;
    const unsigned short* Bbase = Bt + (size_t)n0 * K + koff;
    unsigned short* Cout = ksp ? Cb : Ca;

    floatx16 acc[4][2] = {};
    P8_MAIN_LOOP(32)                            // K-half=2048 -> 32 K-tiles

#pragma unroll
    for (int mt = 0; mt < 4; mt++) {
#pragma unroll
        for (int nt = 0; nt < 2; nt++) {
            int colc = n0 + wn * 64 + nt * 32 + lrow;
#pragma unroll
            for (int reg = 0; reg < 16; reg++) {
                int row = m0 + wm * 128 + mt * 32 + (reg & 3) + 8 * (reg >> 2) + 4 * lhalf;
                Cout[(size_t)row * N + colc] = f2bf(acc[mt][nt][reg]);
            }
        }
    }
}

// ---------------------------------------------------------------------------
// merge: h2pre[i] = bf16(bf2f(Ca[i]) + bf2f(h2pre[i]))  (in-place, elementwise)
// ---------------------------------------------------------------------------
__global__ __launch_bounds__(256) void merge_kernel(
        const unsigned short* __restrict__ Ca, unsigned short* __restrict__ Cb) {
    const uint4* a4 = (const uint4*)Ca;
    uint4* b4 = (uint4*)Cb;
    int base = blockIdx.x * 1024 + threadIdx.x;
#pragma unroll
    for (int j = 0; j < 4; j++) {
        int i = base + j * 256;
        float fa[8], fb[8];
        unpack8(a4[i], fa);
        unpack8(b4[i], fb);
#pragma unroll
        for (int k = 0; k < 8; k++) fa[k] += fb[k];
        b4[i] = pack8(fa);
    }
}

// ---------------------------------------------------------------------------
// Final: aggregate h3 (stride 16), add b3, log_softmax per node.
// ---------------------------------------------------------------------------
__global__ void final_kernel(const float* __restrict__ h3, const int* __restrict__ row_ptr,
                             const int* __restrict__ csr_src, const float* __restrict__ csr_w,
                             const int* __restrict__ deg, const float* __restrict__ b3,
                             float* __restrict__ out) {
    int v = blockIdx.x * blockDim.x + threadIdx.x;
    if (v >= N_NODES) return;
    const float4* h4 = (const float4*)h3;
    float sw = 1.0f / (float)(deg[v] + 1);
    float a[12];
    *(float4*)&a[0] = h4[v * 4];
    *(float4*)&a[4] = h4[v * 4 + 1];
    *(float4*)&a[8] = h4[v * 4 + 2];
    float acc[F_OUT];
#pragma unroll
    for (int c = 0; c < F_OUT; c++) acc[c] = b3[c] + sw * a[c];
    int end = row_ptr[v + 1];
    for (int e = row_ptr[v]; e < end; e++) {
        int s = csr_src[e];
        float w = csr_w[e];
        float bsrc[12];
        *(float4*)&bsrc[0] = h4[s * 4];
        *(float4*)&bsrc[4] = h4[s * 4 + 1];
        *(float4*)&bsrc[8] = h4[s * 4 + 2];
#pragma unroll
        for (int c = 0; c < F_OUT; c++) acc[c] += w * bsrc[c];
    }
    float m = acc[0];
#pragma unroll
    for (int c = 1; c < F_OUT; c++) m = fmaxf(m, acc[c]);
    float ssum = 0.0f;
#pragma unroll
    for (int c = 0; c < F_OUT; c++) ssum += expf(acc[c] - m);
    float l = logf(ssum);
#pragma unroll
    for (int c = 0; c < F_OUT; c++) out[v * F_OUT + c] = acc[c] - m - l;
}

// ---------------------------------------------------------------------------
// Launch (8 dispatches)
// ---------------------------------------------------------------------------
extern "C" void kernel_launch(void* const* d_in, const int* in_sizes, int n_in,
                              void* d_out, int out_size, void* d_ws, size_t ws_size,
                              hipStream_t stream) {
    const float* x  = (const float*)d_in[0];
    const float* W1 = (const float*)d_in[1];
    const float* b1 = (const float*)d_in[2];
    const float* W2 = (const float*)d_in[3];
    const float* b2 = (const float*)d_in[4];
    const float* W3 = (const float*)d_in[5];
    const float* b3 = (const float*)d_in[6];
    const int*   ei = (const int*)d_in[7];
    float* out = (float*)d_out;

    char* p = (char*)d_ws;
    int*   deg     = (int*)p;    p += N_NODES * 4;
    int*   cnt     = (int*)p;    p += N_NODES * 4;
    int*   row_ptr = (int*)p;    p += 33024;
    int*   csr_src = (int*)p;    p += N_EDGES * 4;
    float* csr_w   = (float*)p;  p += N_EDGES * 4;
    float* h3      = (float*)p;  p += N_NODES * H3_STRIDE * 4;
    unsigned short* w3b = (unsigned short*)p; p += (F_OUT * W3B_STRIDE * 2 + 255) / 256 * 256;
    unsigned short* xb    = (unsigned short*)p; p += (size_t)N_NODES * F_IN * 2;
    unsigned short* agg_x = (unsigned short*)p; p += (size_t)N_NODES * F_IN * 2;
    unsigned short* W1t   = (unsigned short*)p; p += (size_t)HID1 * F_IN * 2;
    unsigned short* W2t   = (unsigned short*)p; p += (size_t)HID2 * HID1 * 2;
    unsigned short* h1    = (unsigned short*)p; p += (size_t)N_NODES * HID1 * 2;
    unsigned short* h2pre = (unsigned short*)p; p += (size_t)N_NODES * HID2 * 2;
    // k0-partial of gemm2 overlays xb+agg_x (16 MB, dead after gemm1).
    unsigned short* h2a = xb;

    // Graph preprocessing + all conversions (2 launches)
    hist_scan_kernel<<<1, 1024, 0, stream>>>(ei, deg, row_ptr, cnt);
    megaprep_kernel<<<10497, 256, 0, stream>>>(ei, deg, row_ptr, cnt, csr_src, csr_w,
                                               x, xb, W1, W1t, W2, W2t, W3, w3b);

    // Layer 1: 8-phase pipelined 256^2 GEMM (512 blocks x 512 threads)
    agg1_kernel<<<N_NODES / 4, 256, 0, stream>>>(xb, row_ptr, csr_src, csr_w, deg, agg_x);
    gemm1_pipe8_kernel<<<(N_NODES / 256) * (HID1 / 256), 512, 0, stream>>>(
        agg_x, W1t, b1, h1);

    // Layer 2: split-K=2 8-phase GEMM (256 blocks = full chip) + in-place merge
    gemm2_pipe8_split_kernel<<<256, 512, 0, stream>>>(h1, W2t, h2a, h2pre);
    merge_kernel<<<1024, 256, 0, stream>>>(h2a, h2pre);

    // Layer 2 aggregation + Layer 3 GEMM fused
    agg2_gemm3_kernel<<<N_NODES / 2, 256, 0, stream>>>(h2pre, row_ptr, csr_src, csr_w,
                                                       deg, b2, w3b, h3);

    // Output
    final_kernel<<<N_NODES / 256, 256, 0, stream>>>(h3, row_ptr, csr_src, csr_w, deg, b3, out);
}